// Round 9
// baseline (539.560 us; speedup 1.0000x reference)
//
#include <hip/hip_runtime.h>
#include <math.h>

// ---------------------------------------------------------------------------
// GCN 5-layer forward, dinv-prescaled formulation.
//   agg[v] = dinv[v] * ( sum_{s in N(v)} hs[s] + hs[v] ),  hs = dinv (.) h.
// Layer plan (narrow-side aggregation; D(XW)=(DX)W commuting):
//   L1: agg2(xs=dinv*x) -> gemm 2->128 +b1 relu *dinv
//   L2: gemm 128->128 (cm16 out) ; agg128x2 +b2 relu *dinv (cm16)
//   L3: gemm 128->32 (cm16 in) ; agg32mm: agg +b3 relu *dinv THEN @W4 fused
//   L4: agg32 +b4 relu *dinv
//   L5: agg32fin: raw agg THEN (@W5+b5).relu@Wl+bl fused -> out
// R22: agg128x -> agg128x2: 8 chunks of 16 cols, slice = 3.2MB <= 4MB L2,
//   BOTH dst-halves of chunk c pinned to XCD c (class=blockIdx&15, chunk=
//   blockIdx&7 -> XCD, half=(blockIdx>>3)&1) -> per-XCD hot gather ws is ONE
//   resident slice. 4-lane node-groups keep 1 float4/lane: wave load still
//   moves 1KB (16 grp x 64B) -> bytes/instr unchanged; edge visits 4->8
//   (VALU 26->~50%, non-binding at the BW wall). R15's chunking failure was
//   a latency-bound kernel with 4x instr/byte — regime differs (rule #23).
//   gemm L2 COUT=16, gemm L3 CIN=16 (index-only, 64B-contig preserved).
//   Predicted: FETCH 327->~120-180MB, dur 98.6->~55-75us, total ~470-490.
// R21 (511us): fused gemm_L4 into agg32mm + gemm_final into agg32fin
//   (-15us, both epilogues hidden under latency-bound gathers).
// R20/R19/R18/R17: persistent phase-barrier family CLOSED (3 strikes:
//   spills / global-barrier collapse / per-XCD barrier deadlock-to-cap;
//   FETCH 167MB proved quartile-sweep locality but sync cost ate it).
// R16 (526us base): quartile CSR build. R15 (REVERTED): chunking on
//   latency-bound agg32 = 4x instrs for fewer bytes. R14: XCD-sliced cm32
//   agg128 127->98us, FETCH 414->328 (12.8MB slice > L2, hit ~63%).
// Structural walls (measured): agg32 ~45us each; fill/count atomic floors;
//   fp32 vector-ALU gemms (no fp32 MFMA; plain bf16 blows 7.9e-5 absmax).
// ---------------------------------------------------------------------------

static inline int cdiv(int a, int b) { return (a + b - 1) / b; }

__global__ void zero_i32(int* __restrict__ p, int n) {
    int i = blockIdx.x * 256 + threadIdx.x;
    if (i < n) p[i] = 0;
}

// Degree count per (dst, src-quartile): atomics into cntq[4N].
__global__ void count_q(const int* __restrict__ src, const int* __restrict__ dst,
                        int* __restrict__ cntq, int E, int q1) {
    int e = blockIdx.x * 256 + threadIdx.x;
    if (e < E) {
        int s = src[e];
        int q = (s >= q1) + (s >= 2 * q1) + (s >= 3 * q1);
        atomicAdd(&cntq[dst[e] * 4 + q], 1);
    }
}

// Inclusive scan per 256-block of per-node TOTALS; block totals to bsum.
__global__ void scan1q(const int* __restrict__ cntq, int* __restrict__ off,
                       int* __restrict__ bsum, int n) {
    __shared__ int sm[256];
    int i = blockIdx.x * 256 + threadIdx.x;
    int v = 0;
    if (i < n) {
        int4 c = *reinterpret_cast<const int4*>(cntq + 4 * (size_t)i);
        v = c.x + c.y + c.z + c.w;
    }
    sm[threadIdx.x] = v;
    __syncthreads();
    for (int ofs = 1; ofs < 256; ofs <<= 1) {
        int t = (threadIdx.x >= (unsigned)ofs) ? sm[threadIdx.x - ofs] : 0;
        __syncthreads();
        sm[threadIdx.x] += t;
        __syncthreads();
    }
    if (i < n) off[i] = sm[threadIdx.x];
    if (threadIdx.x == 255) bsum[blockIdx.x] = sm[255];
}

// Exclusive scan of block sums (nb <= 512).
__global__ void scan2(const int* __restrict__ bsum, int* __restrict__ bpre,
                      int nb, int* __restrict__ off, int N, int E) {
    __shared__ int sm[512];
    int t = threadIdx.x;
    sm[t] = (t < nb) ? bsum[t] : 0;
    __syncthreads();
    for (int ofs = 1; ofs < 512; ofs <<= 1) {
        int v = (t >= ofs) ? sm[t - ofs] : 0;
        __syncthreads();
        sm[t] += v;
        __syncthreads();
    }
    if (t < nb) bpre[t] = sm[t] - bsum[t];
    if (t == 0) off[N] = E;
}

// Fused: finalize off (exclusive), seed 4 quartile cursors per node,
// dinv=1/sqrt(deg+1), xs = dinv * x.
__global__ void scan3_fused(const int* __restrict__ cntq, const int* __restrict__ bpre,
                            int* __restrict__ off, int* __restrict__ cursorq,
                            const float* __restrict__ x, float* __restrict__ dinv,
                            float* __restrict__ xs, int n) {
    int i = blockIdx.x * 256 + threadIdx.x;
    if (i < n) {
        int4 cq = *reinterpret_cast<const int4*>(cntq + 4 * (size_t)i);
        int c = cq.x + cq.y + cq.z + cq.w;
        int o = off[i] - c + bpre[blockIdx.x];
        off[i] = o;
        int4 cur;
        cur.x = o;
        cur.y = o + cq.x;
        cur.z = o + cq.x + cq.y;
        cur.w = o + cq.x + cq.y + cq.z;
        *reinterpret_cast<int4*>(cursorq + 4 * (size_t)i) = cur;
        float dv = 1.0f / sqrtf((float)c + 1.0f);
        dinv[i] = dv;
        float2 xv = *reinterpret_cast<const float2*>(x + 2 * (size_t)i);
        *reinterpret_cast<float2*>(xs + 2 * (size_t)i) = float2{dv * xv.x, dv * xv.y};
    }
}

// XCD-class-filtered CSR fill with src-quartile bucketing.
__global__ __launch_bounds__(256) void fill_ranged(const int* __restrict__ src,
                                                   const int* __restrict__ dst,
                                                   int* __restrict__ cursorq,
                                                   int* __restrict__ csr,
                                                   int E, int N, int echunk, int q1) {
    int cls = blockIdx.x & 7;
    int chunk = blockIdx.x >> 3;
    int per = (N + 7) >> 3;
    int lo = cls * per;
    int hi = lo + per; if (hi > N) hi = N;
    int e0 = chunk * echunk;
    int e1 = e0 + echunk; if (e1 > E) e1 = E;
    for (int e = e0 + (int)threadIdx.x; e < e1; e += 256) {
        int d = dst[e];
        if (d >= lo && d < hi) {
            int s = src[e];
            int q = (s >= q1) + (s >= 2 * q1) + (s >= 3 * q1);
            int p = atomicAdd(&cursorq[d * 4 + q], 1);
            csr[p] = s;
        }
    }
}

// ---------------------------------------------------------------------------
// Aggregation of pre-scaled [N,2] input: one thread per node.
// ---------------------------------------------------------------------------
__global__ __launch_bounds__(256) void agg2_kernel(const float* __restrict__ xs,
                                                   const int* __restrict__ off,
                                                   const int* __restrict__ csr,
                                                   const float* __restrict__ dinv,
                                                   float* __restrict__ out, int n) {
    int v = blockIdx.x * 256 + threadIdx.x;
    if (v >= n) return;
    float a0 = 0.f, a1 = 0.f;
    int e0 = off[v], e1 = off[v + 1];
    for (int e = e0; e < e1; e++) {
        int s = csr[e];
        float2 q = *reinterpret_cast<const float2*>(xs + 2 * (size_t)s);
        a0 += q.x;
        a1 += q.y;
    }
    float dv = dinv[v];
    float2 xv = *reinterpret_cast<const float2*>(xs + 2 * (size_t)v);
    *reinterpret_cast<float2*>(out + 2 * (size_t)v) =
        float2{dv * (a0 + xv.x), dv * (a1 + xv.y)};
}

// ---------------------------------------------------------------------------
// agg128x2: F=128 aggregation, L2-RESIDENT slices. h chunk-major hc[8][N][16].
// class = blockIdx&15: chunk = blockIdx&7 (-> XCD via &7 round-robin),
// half = (blockIdx>>3)&1. Both halves of chunk c run on XCD c, so the XCD's
// hot gather set is ONE 3.2MB slice (csr/out streamed). 4 lanes/node, one
// float4/lane (64B/edge-visit); wave load instr still moves 16x64B = 1KB.
// ---------------------------------------------------------------------------
template <bool BR, bool PS>
__global__ __launch_bounds__(256) void agg128x2_kernel(const float* __restrict__ hc,
                                                       const int* __restrict__ off,
                                                       const int* __restrict__ csr,
                                                       const float* __restrict__ dinv,
                                                       const float* __restrict__ bias,
                                                       float* __restrict__ outc, int n) {
    int chunk = blockIdx.x & 7;
    int half = (blockIdx.x >> 3) & 1;
    int n2 = (n + 1) >> 1;
    int lo = half * n2;
    int hi = lo + n2; if (hi > n) hi = n;

    const float* __restrict__ h = hc + (size_t)chunk * n * 16;
    float* __restrict__ out = outc + (size_t)chunk * n * 16;

    int tid = threadIdx.x;
    int lane = tid & 63;
    int sl = lane & 3;
    int subbase = lane & ~3;
    int wave = tid >> 6;
    int v = lo + (blockIdx.x >> 4) * 64 + wave * 16 + (lane >> 2);
    if (v >= hi) return;

    int start = off[v];
    int end = off[v + 1];

    float4 acc = {0.f, 0.f, 0.f, 0.f};

    for (int base = start; base < end; base += 8) {
        int m = end - base;
        if (m > 8) m = 8;
        int idxA = (sl < m) ? csr[base + sl] : 0;
        int idxB = (4 + sl < m) ? csr[base + 4 + sl] : 0;
        if (m == 8) {
            float4 hb[8];
#pragma unroll
            for (int u = 0; u < 8; u++) {
                int s = __shfl((u < 4) ? idxA : idxB, subbase + (u & 3));
                hb[u] = *reinterpret_cast<const float4*>(h + (size_t)s * 16 + sl * 4);
            }
#pragma unroll
            for (int u = 0; u < 8; u++) {
                acc.x += hb[u].x; acc.y += hb[u].y; acc.z += hb[u].z; acc.w += hb[u].w;
            }
        } else {
            int ma = (m < 4) ? m : 4;
            int i = 0;
            if (ma == 4) {
                float4 hb[4];
#pragma unroll
                for (int u = 0; u < 4; u++) {
                    int s = __shfl(idxA, subbase + u);
                    hb[u] = *reinterpret_cast<const float4*>(h + (size_t)s * 16 + sl * 4);
                }
#pragma unroll
                for (int u = 0; u < 4; u++) {
                    acc.x += hb[u].x; acc.y += hb[u].y; acc.z += hb[u].z; acc.w += hb[u].w;
                }
                i = 4;
            } else {
                if (i + 2 <= ma) {
                    int s0 = __shfl(idxA, subbase + i);
                    int s1 = __shfl(idxA, subbase + i + 1);
                    float4 h0 = *reinterpret_cast<const float4*>(h + (size_t)s0 * 16 + sl * 4);
                    float4 h1 = *reinterpret_cast<const float4*>(h + (size_t)s1 * 16 + sl * 4);
                    acc.x += h0.x + h1.x; acc.y += h0.y + h1.y;
                    acc.z += h0.z + h1.z; acc.w += h0.w + h1.w;
                    i += 2;
                }
                if (i < ma) {
                    int s0 = __shfl(idxA, subbase + i);
                    float4 h0 = *reinterpret_cast<const float4*>(h + (size_t)s0 * 16 + sl * 4);
                    acc.x += h0.x; acc.y += h0.y; acc.z += h0.z; acc.w += h0.w;
                }
            }
            if (m > 4) {
                int mb = m - 4;
                int j = 0;
                if (j + 2 <= mb) {
                    int s0 = __shfl(idxB, subbase + j);
                    int s1 = __shfl(idxB, subbase + j + 1);
                    float4 h0 = *reinterpret_cast<const float4*>(h + (size_t)s0 * 16 + sl * 4);
                    float4 h1 = *reinterpret_cast<const float4*>(h + (size_t)s1 * 16 + sl * 4);
                    acc.x += h0.x + h1.x; acc.y += h0.y + h1.y;
                    acc.z += h0.z + h1.z; acc.w += h0.w + h1.w;
                    j += 2;
                }
                if (j < mb) {
                    int s0 = __shfl(idxB, subbase + j);
                    float4 h0 = *reinterpret_cast<const float4*>(h + (size_t)s0 * 16 + sl * 4);
                    acc.x += h0.x; acc.y += h0.y; acc.z += h0.z; acc.w += h0.w;
                }
            }
        }
    }

    float dv = dinv[v];
    float4 hv = *reinterpret_cast<const float4*>(h + (size_t)v * 16 + sl * 4);
    float o0 = dv * (acc.x + hv.x);
    float o1 = dv * (acc.y + hv.y);
    float o2 = dv * (acc.z + hv.z);
    float o3 = dv * (acc.w + hv.w);
    if constexpr (BR) {
        float4 b = *reinterpret_cast<const float4*>(bias + chunk * 16 + sl * 4);
        o0 = fmaxf(o0 + b.x, 0.f);
        o1 = fmaxf(o1 + b.y, 0.f);
        o2 = fmaxf(o2 + b.z, 0.f);
        o3 = fmaxf(o3 + b.w, 0.f);
    }
    if constexpr (PS) {
        o0 *= dv; o1 *= dv; o2 *= dv; o3 *= dv;
    }
    *reinterpret_cast<float4*>(out + (size_t)v * 16 + sl * 4) = float4{o0, o1, o2, o3};
}

// ---------------------------------------------------------------------------
// Shared agg32 gather body: 8 lanes/node, lane owns 4 cols. Returns acc.
// ---------------------------------------------------------------------------
__device__ __forceinline__ float4 agg32_gather(const float* __restrict__ h,
                                               const int* __restrict__ csr,
                                               int start, int end,
                                               int sl, int subbase) {
    float4 acc = {0.f, 0.f, 0.f, 0.f};
    for (int base = start; base < end; base += 16) {
        int m = end - base;
        if (m > 16) m = 16;
        int idxA = (sl < m) ? csr[base + sl] : 0;
        int idxB = (8 + sl < m) ? csr[base + 8 + sl] : 0;
        if (m == 16) {
            float4 hb[16];
#pragma unroll
            for (int u = 0; u < 16; u++) {
                int s = __shfl((u < 8) ? idxA : idxB, subbase + (u & 7));
                hb[u] = *reinterpret_cast<const float4*>(h + (size_t)s * 32 + sl * 4);
            }
#pragma unroll
            for (int u = 0; u < 16; u++) {
                acc.x += hb[u].x; acc.y += hb[u].y; acc.z += hb[u].z; acc.w += hb[u].w;
            }
        } else {
            int ma = (m < 8) ? m : 8;
            int i = 0;
            for (; i + 4 <= ma; i += 4) {
                float4 hb[4];
#pragma unroll
                for (int u = 0; u < 4; u++) {
                    int s = __shfl(idxA, subbase + i + u);
                    hb[u] = *reinterpret_cast<const float4*>(h + (size_t)s * 32 + sl * 4);
                }
#pragma unroll
                for (int u = 0; u < 4; u++) {
                    acc.x += hb[u].x; acc.y += hb[u].y; acc.z += hb[u].z; acc.w += hb[u].w;
                }
            }
            if (i + 2 <= ma) {
                int s0 = __shfl(idxA, subbase + i);
                int s1 = __shfl(idxA, subbase + i + 1);
                float4 h0 = *reinterpret_cast<const float4*>(h + (size_t)s0 * 32 + sl * 4);
                float4 h1 = *reinterpret_cast<const float4*>(h + (size_t)s1 * 32 + sl * 4);
                acc.x += h0.x + h1.x; acc.y += h0.y + h1.y;
                acc.z += h0.z + h1.z; acc.w += h0.w + h1.w;
                i += 2;
            }
            if (i < ma) {
                int s0 = __shfl(idxA, subbase + i);
                float4 h0 = *reinterpret_cast<const float4*>(h + (size_t)s0 * 32 + sl * 4);
                acc.x += h0.x; acc.y += h0.y; acc.z += h0.z; acc.w += h0.w;
            }
            if (m > 8) {
                int mb = m - 8;
                int j = 0;
                for (; j + 4 <= mb; j += 4) {
                    float4 hb[4];
#pragma unroll
                    for (int u = 0; u < 4; u++) {
                        int s = __shfl(idxB, subbase + j + u);
                        hb[u] = *reinterpret_cast<const float4*>(h + (size_t)s * 32 + sl * 4);
                    }
#pragma unroll
                    for (int u = 0; u < 4; u++) {
                        acc.x += hb[u].x; acc.y += hb[u].y; acc.z += hb[u].z; acc.w += hb[u].w;
                    }
                }
                if (j + 2 <= mb) {
                    int s0 = __shfl(idxB, subbase + j);
                    int s1 = __shfl(idxB, subbase + j + 1);
                    float4 h0 = *reinterpret_cast<const float4*>(h + (size_t)s0 * 32 + sl * 4);
                    float4 h1 = *reinterpret_cast<const float4*>(h + (size_t)s1 * 32 + sl * 4);
                    acc.x += h0.x + h1.x; acc.y += h0.y + h1.y;
                    acc.z += h0.z + h1.z; acc.w += h0.w + h1.w;
                    j += 2;
                }
                if (j < mb) {
                    int s0 = __shfl(idxB, subbase + j);
                    float4 h0 = *reinterpret_cast<const float4*>(h + (size_t)s0 * 32 + sl * 4);
                    acc.x += h0.x; acc.y += h0.y; acc.z += h0.z; acc.w += h0.w;
                }
            }
        }
    }
    return acc;
}

// ---------------------------------------------------------------------------
// agg32: plain F=32 aggregation (+bias/relu BR, post-scale PS).
// ---------------------------------------------------------------------------
template <bool BR, bool PS>
__global__ __launch_bounds__(256) void agg32_kernel(const float* __restrict__ h,
                                                    const int* __restrict__ off,
                                                    const int* __restrict__ csr,
                                                    const float* __restrict__ dinv,
                                                    const float* __restrict__ bias,
                                                    float* __restrict__ out, int n) {
    int tid = threadIdx.x;
    int lane = tid & 63;
    int sl = lane & 7;
    int subbase = lane & ~7;
    int wave = tid >> 6;
    int v = blockIdx.x * 32 + wave * 8 + (lane >> 3);
    if (v >= n) return;

    float4 acc = agg32_gather(h, csr, off[v], off[v + 1], sl, subbase);

    float dv = dinv[v];
    float4 hv = *reinterpret_cast<const float4*>(h + (size_t)v * 32 + sl * 4);
    float o0 = dv * (acc.x + hv.x);
    float o1 = dv * (acc.y + hv.y);
    float o2 = dv * (acc.z + hv.z);
    float o3 = dv * (acc.w + hv.w);
    if constexpr (BR) {
        float4 b = *reinterpret_cast<const float4*>(bias + sl * 4);
        o0 = fmaxf(o0 + b.x, 0.f);
        o1 = fmaxf(o1 + b.y, 0.f);
        o2 = fmaxf(o2 + b.z, 0.f);
        o3 = fmaxf(o3 + b.w, 0.f);
    }
    if constexpr (PS) {
        o0 *= dv; o1 *= dv; o2 *= dv; o3 *= dv;
    }
    *reinterpret_cast<float4*>(out + (size_t)v * 32 + sl * 4) = float4{o0, o1, o2, o3};
}

// ---------------------------------------------------------------------------
// agg32mm: agg32 (+b, relu, *dv) FUSED with @W (32x32) -> out = (D.x3)@W4.
// W staged in 4KB LDS; per node: 32 shfl broadcasts + 32 float4 FMAs,
// hidden under the latency-bound gather. Output row-major [N][32].
// ---------------------------------------------------------------------------
__global__ __launch_bounds__(256) void agg32mm_kernel(const float* __restrict__ h,
                                                      const int* __restrict__ off,
                                                      const int* __restrict__ csr,
                                                      const float* __restrict__ dinv,
                                                      const float* __restrict__ bias,
                                                      const float* __restrict__ W,
                                                      float* __restrict__ out, int n) {
    __shared__ float Ws[32 * 32];
    int tid = threadIdx.x;
    *reinterpret_cast<float4*>(&Ws[tid * 4]) =
        *reinterpret_cast<const float4*>(W + tid * 4);
    __syncthreads();

    int lane = tid & 63;
    int sl = lane & 7;
    int subbase = lane & ~7;
    int wave = tid >> 6;
    int v = blockIdx.x * 32 + wave * 8 + (lane >> 3);
    if (v >= n) return;

    float4 acc = agg32_gather(h, csr, off[v], off[v + 1], sl, subbase);

    float dv = dinv[v];
    float4 hv = *reinterpret_cast<const float4*>(h + (size_t)v * 32 + sl * 4);
    float4 b = *reinterpret_cast<const float4*>(bias + sl * 4);
    float o0 = fmaxf(dv * (acc.x + hv.x) + b.x, 0.f) * dv;
    float o1 = fmaxf(dv * (acc.y + hv.y) + b.y, 0.f) * dv;
    float o2 = fmaxf(dv * (acc.z + hv.z) + b.z, 0.f) * dv;
    float o3 = fmaxf(dv * (acc.w + hv.w) + b.w, 0.f) * dv;

    // y[4sl..4sl+3] = sum_k x[k] * W[k][4sl..]; x[k] broadcast via shfl.
    float y0 = 0.f, y1 = 0.f, y2 = 0.f, y3 = 0.f;
#pragma unroll
    for (int q = 0; q < 8; q++) {
        float x0 = __shfl(o0, subbase + q);
        float x1 = __shfl(o1, subbase + q);
        float x2 = __shfl(o2, subbase + q);
        float x3 = __shfl(o3, subbase + q);
        float4 w0 = *reinterpret_cast<const float4*>(&Ws[(4 * q + 0) * 32 + sl * 4]);
        float4 w1 = *reinterpret_cast<const float4*>(&Ws[(4 * q + 1) * 32 + sl * 4]);
        float4 w2 = *reinterpret_cast<const float4*>(&Ws[(4 * q + 2) * 32 + sl * 4]);
        float4 w3 = *reinterpret_cast<const float4*>(&Ws[(4 * q + 3) * 32 + sl * 4]);
        y0 += x0 * w0.x + x1 * w1.x + x2 * w2.x + x3 * w3.x;
        y1 += x0 * w0.y + x1 * w1.y + x2 * w2.y + x3 * w3.y;
        y2 += x0 * w0.z + x1 * w1.z + x2 * w2.z + x3 * w3.z;
        y3 += x0 * w0.w + x1 * w1.w + x2 * w2.w + x3 * w3.w;
    }
    *reinterpret_cast<float4*>(out + (size_t)v * 32 + sl * 4) = float4{y0, y1, y2, y3};
}

// ---------------------------------------------------------------------------
// agg32fin: raw agg32 FUSED with (t@W5+b5).relu @ Wl + bl -> out[v] scalar.
// W5 (8KB), b5, wl staged in LDS; lane owns 8 of 64 mid-cols; 8-lane
// shfl-xor reduce; lane0-of-8 writes.
// ---------------------------------------------------------------------------
__global__ __launch_bounds__(256) void agg32fin_kernel(const float* __restrict__ h,
                                                       const int* __restrict__ off,
                                                       const int* __restrict__ csr,
                                                       const float* __restrict__ dinv,
                                                       const float* __restrict__ W5,
                                                       const float* __restrict__ b5,
                                                       const float* __restrict__ Wl,
                                                       const float* __restrict__ bl,
                                                       float* __restrict__ out, int n) {
    __shared__ float W5s[32 * 64];
    __shared__ float b5s[64];
    __shared__ float wls[64];
    int tid = threadIdx.x;
    *reinterpret_cast<float4*>(&W5s[tid * 8]) =
        *reinterpret_cast<const float4*>(W5 + tid * 8);
    *reinterpret_cast<float4*>(&W5s[tid * 8 + 4]) =
        *reinterpret_cast<const float4*>(W5 + tid * 8 + 4);
    if (tid < 64) b5s[tid] = b5[tid];
    else if (tid < 128) wls[tid - 64] = Wl[tid - 64];
    __syncthreads();

    int lane = tid & 63;
    int sl = lane & 7;
    int subbase = lane & ~7;
    int wave = tid >> 6;
    int v = blockIdx.x * 32 + wave * 8 + (lane >> 3);
    if (v >= n) return;

    float4 acc = agg32_gather(h, csr, off[v], off[v + 1], sl, subbase);

    float dv = dinv[v];
    float4 hv = *reinterpret_cast<const float4*>(h + (size_t)v * 32 + sl * 4);
    float t0 = dv * (acc.x + hv.x);
    float t1 = dv * (acc.y + hv.y);
    float t2 = dv * (acc.z + hv.z);
    float t3 = dv * (acc.w + hv.w);

    // y[sl*8 .. sl*8+7] = sum_k t[k] * W5[k][sl*8..]
    float y0 = 0.f, y1 = 0.f, y2 = 0.f, y3 = 0.f;
    float y4 = 0.f, y5 = 0.f, y6 = 0.f, y7 = 0.f;
#pragma unroll
    for (int q = 0; q < 8; q++) {
        float x0 = __shfl(t0, subbase + q);
        float x1 = __shfl(t1, subbase + q);
        float x2 = __shfl(t2, subbase + q);
        float x3 = __shfl(t3, subbase + q);
#pragma unroll
        for (int r = 0; r < 4; r++) {
            float xv = (r == 0) ? x0 : (r == 1) ? x1 : (r == 2) ? x2 : x3;
            const float* wr = &W5s[(4 * q + r) * 64 + sl * 8];
            float4 wa = *reinterpret_cast<const float4*>(wr);
            float4 wb = *reinterpret_cast<const float4*>(wr + 4);
            y0 += xv * wa.x; y1 += xv * wa.y; y2 += xv * wa.z; y3 += xv * wa.w;
            y4 += xv * wb.x; y5 += xv * wb.y; y6 += xv * wb.z; y7 += xv * wb.w;
        }
    }
    float4 ba = *reinterpret_cast<const float4*>(&b5s[sl * 8]);
    float4 bb = *reinterpret_cast<const float4*>(&b5s[sl * 8 + 4]);
    float4 wa = *reinterpret_cast<const float4*>(&wls[sl * 8]);
    float4 wb = *reinterpret_cast<const float4*>(&wls[sl * 8 + 4]);
    float z = fmaxf(y0 + ba.x, 0.f) * wa.x + fmaxf(y1 + ba.y, 0.f) * wa.y +
              fmaxf(y2 + ba.z, 0.f) * wa.z + fmaxf(y3 + ba.w, 0.f) * wa.w +
              fmaxf(y4 + bb.x, 0.f) * wb.x + fmaxf(y5 + bb.y, 0.f) * wb.y +
              fmaxf(y6 + bb.z, 0.f) * wb.z + fmaxf(y7 + bb.w, 0.f) * wb.w;
    z += __shfl_xor(z, 4);
    z += __shfl_xor(z, 2);
    z += __shfl_xor(z, 1);
    if (sl == 0) out[v] = z + bl[0];
}

// ---------------------------------------------------------------------------
// Register-tiled GEMM: h[N,F] = x[N,K] @ W[K,F]; epilogue +bias/relu (BR),
// *dinv[row] (PS). KC=32 (KCP=36 breaks pow-2 banks).
// CIN/COUT: 0 = row-major, 16 = chunk-major [K/16][N][16] in / [F/16][N][16]
// out (for agg128x2). All accesses stay within one 16-col chunk (kk and cb
// offsets are 8/4-aligned), so >=64B-contiguity is preserved.
// ---------------------------------------------------------------------------
template <int K, int F, bool BR, bool PS, int CIN = 0, int COUT = 0>
__global__ __launch_bounds__(256, 4) void gemm_tiled(const float* __restrict__ x,
                                                     const float* __restrict__ W,
                                                     const float* __restrict__ bias,
                                                     const float* __restrict__ dinv,
                                                     float* __restrict__ h, int n) {
    constexpr int KC = 32;
    constexpr int KCP = 36;             // padded row stride (144 B, 16B-aligned)
    constexpr int ROWS = 64;
    constexpr int TPC = F / 4;
    constexpr int RT = 256 / TPC;
    constexpr int RPT = ROWS / RT;
    static_assert(K % KC == 0, "K must be a multiple of 32");

    __shared__ float Ws[KC * F];
    __shared__ float Xs[ROWS * KCP];

    const int tid = threadIdx.x;
    const int cb = (tid % TPC) * 4;
    const int tr = tid / TPC;
    const int row0 = blockIdx.x * ROWS;

    float acc[RPT][4];
#pragma unroll
    for (int r = 0; r < RPT; r++)
#pragma unroll
        for (int j = 0; j < 4; j++) acc[r][j] = 0.f;

#pragma unroll 1
    for (int k0 = 0; k0 < K; k0 += KC) {
        __syncthreads();
        {
            int r = tid >> 2;
            int kk = (tid & 3) * 8;
            int gr = row0 + r;
            float4 v0 = {0.f, 0.f, 0.f, 0.f}, v1 = {0.f, 0.f, 0.f, 0.f};
            if (gr < n) {
                if constexpr (CIN == 16) {
                    int kc = k0 + kk;
                    const float* xb = x + (size_t)(kc >> 4) * n * 16 + (size_t)gr * 16 + (kc & 15);
                    v0 = *reinterpret_cast<const float4*>(xb);
                    v1 = *reinterpret_cast<const float4*>(xb + 4);
                } else {
                    v0 = *reinterpret_cast<const float4*>(x + (size_t)gr * K + k0 + kk);
                    v1 = *reinterpret_cast<const float4*>(x + (size_t)gr * K + k0 + kk + 4);
                }
            }
            *reinterpret_cast<float4*>(&Xs[r * KCP + kk]) = v0;
            *reinterpret_cast<float4*>(&Xs[r * KCP + kk + 4]) = v1;
        }
        for (int i = tid; i < KC * F / 4; i += 256) {
            *reinterpret_cast<float4*>(&Ws[i * 4]) =
                *reinterpret_cast<const float4*>(W + (size_t)k0 * F + i * 4);
        }
        __syncthreads();

#pragma unroll 4
        for (int kk4 = 0; kk4 < KC; kk4 += 4) {
            float4 xr[RPT];
#pragma unroll
            for (int r = 0; r < RPT; r++)
                xr[r] = *reinterpret_cast<const float4*>(&Xs[(tr * RPT + r) * KCP + kk4]);
#pragma unroll
            for (int j = 0; j < 4; j++) {
                float4 w = *reinterpret_cast<const float4*>(&Ws[(kk4 + j) * F + cb]);
#pragma unroll
                for (int r = 0; r < RPT; r++) {
                    float xv = (j == 0) ? xr[r].x : (j == 1) ? xr[r].y
                             : (j == 2) ? xr[r].z : xr[r].w;
                    acc[r][0] += xv * w.x;
                    acc[r][1] += xv * w.y;
                    acc[r][2] += xv * w.z;
                    acc[r][3] += xv * w.w;
                }
            }
        }
    }

    float4 b = float4{0.f, 0.f, 0.f, 0.f};
    if constexpr (BR) b = *reinterpret_cast<const float4*>(bias + cb);
#pragma unroll
    for (int r = 0; r < RPT; r++) {
        int row = row0 + tr * RPT + r;
        if (row < n) {
            float o0 = acc[r][0], o1 = acc[r][1], o2 = acc[r][2], o3 = acc[r][3];
            if constexpr (BR) {
                o0 = fmaxf(o0 + b.x, 0.f);
                o1 = fmaxf(o1 + b.y, 0.f);
                o2 = fmaxf(o2 + b.z, 0.f);
                o3 = fmaxf(o3 + b.w, 0.f);
            }
            if constexpr (PS) {
                float dv = dinv[row];
                o0 *= dv; o1 *= dv; o2 *= dv; o3 *= dv;
            }
            if constexpr (COUT == 16) {
                float* hb = h + (size_t)(cb >> 4) * n * 16 + (size_t)row * 16 + (cb & 15);
                *reinterpret_cast<float4*>(hb) = float4{o0, o1, o2, o3};
            } else {
                *reinterpret_cast<float4*>(&h[(size_t)row * F + cb]) = float4{o0, o1, o2, o3};
            }
        }
    }
}

// Simple GEMM for K=2 (layer 1), epilogue +bias/relu (BR), *dinv (PS).
template <int K, int F, bool BR, bool PS>
__global__ __launch_bounds__(256, 4) void gemm_small(const float* __restrict__ x,
                                                     const float* __restrict__ W,
                                                     const float* __restrict__ bias,
                                                     const float* __restrict__ dinv,
                                                     float* __restrict__ h, int n) {
    constexpr int TPR = F / 4;
    constexpr int ROWS = 256 / TPR;
    __shared__ float Ws[K * F];
    for (int i = threadIdx.x; i < K * F; i += 256) Ws[i] = W[i];
    __syncthreads();

    int tid = threadIdx.x;
    int cb = (tid % TPR) * 4;
    int r = blockIdx.x * ROWS + tid / TPR;
    if (r >= n) return;

    const float* xr = x + (size_t)r * K;
    float a0 = 0.f, a1 = 0.f, a2 = 0.f, a3 = 0.f;
#pragma unroll
    for (int k = 0; k < K; k++) {
        float xv = xr[k];
        float4 w = *reinterpret_cast<const float4*>(&Ws[k * F + cb]);
        a0 += xv * w.x; a1 += xv * w.y; a2 += xv * w.z; a3 += xv * w.w;
    }
    if constexpr (BR) {
        float4 b = *reinterpret_cast<const float4*>(bias + cb);
        a0 = fmaxf(a0 + b.x, 0.f);
        a1 = fmaxf(a1 + b.y, 0.f);
        a2 = fmaxf(a2 + b.z, 0.f);
        a3 = fmaxf(a3 + b.w, 0.f);
    }
    if constexpr (PS) {
        float dv = dinv[r];
        a0 *= dv; a1 *= dv; a2 *= dv; a3 *= dv;
    }
    *reinterpret_cast<float4*>(&h[(size_t)r * F + cb]) = float4{a0, a1, a2, a3};
}

extern "C" void kernel_launch(void* const* d_in, const int* in_sizes, int n_in,
                              void* d_out, int out_size, void* d_ws, size_t ws_size,
                              hipStream_t stream) {
    const float* x = (const float*)d_in[0];
    const int* ei = (const int*)d_in[1];
    const float* W1 = (const float*)d_in[3];
    const float* b1 = (const float*)d_in[4];
    const float* W2 = (const float*)d_in[5];
    const float* b2 = (const float*)d_in[6];
    const float* W3 = (const float*)d_in[7];
    const float* b3 = (const float*)d_in[8];
    const float* W4 = (const float*)d_in[9];
    const float* b4 = (const float*)d_in[10];
    const float* W5 = (const float*)d_in[11];
    const float* b5 = (const float*)d_in[12];
    const float* Wl = (const float*)d_in[13];
    const float* bl = (const float*)d_in[14];

    const int N = in_sizes[0] / 2;
    const int E = in_sizes[1] / 2;
    const int* src = ei;
    const int* dst = ei + E;

    char* wp = (char*)d_ws;
    auto alloc = [&](size_t bytes) -> void* {
        void* p = wp;
        wp += ((bytes + 255) / 256) * 256;
        return p;
    };
    int* cntq = (int*)alloc((size_t)N * 4 * 4);
    int* off = (int*)alloc((size_t)(N + 1) * 4);
    int* cursorq = (int*)alloc((size_t)N * 4 * 4);
    int* bsum = (int*)alloc(512 * 4);
    int* bpre = (int*)alloc(512 * 4);
    int* csr = (int*)alloc((size_t)E * 4);
    float* dinv = (float*)alloc((size_t)N * 4);
    float* xs2 = (float*)alloc((size_t)N * 2 * 4);
    float* t2 = (float*)alloc((size_t)N * 2 * 4);
    float* bufA = (float*)alloc((size_t)N * 128 * 4);
    float* bufB = (float*)alloc((size_t)N * 128 * 4);

    const int gN = cdiv(N, 256);
    const int gE = cdiv(E, 256);
    const int nb = gN;
    const int gT = cdiv(N, 64);
    const int q1 = (N + 3) / 4;         // src quartile width

    // Ranged fill grid: 8 classes x 128 chunks.
    const int NCHUNK = 128;
    const int echunk = cdiv(E, NCHUNK);
    const int gR = 8 * NCHUNK;

    // agg128x2 grid: 16 classes (8 col-chunks x 2 dst-halves; both halves of
    // chunk c land on XCD c via blockIdx&7) x node-groups of 64.
    const int gX2 = 16 * cdiv((N + 1) / 2, 64);
    const int gA = cdiv(N, 32);

    // --- CSR build (src-quartile-bucketed edge order) ---
    zero_i32<<<cdiv(4 * N, 256), 256, 0, stream>>>(cntq, 4 * N);
    count_q<<<gE, 256, 0, stream>>>(src, dst, cntq, E, q1);
    scan1q<<<nb, 256, 0, stream>>>(cntq, off, bsum, N);
    scan2<<<1, 512, 0, stream>>>(bsum, bpre, nb, off, N, E);
    scan3_fused<<<nb, 256, 0, stream>>>(cntq, bpre, off, cursorq, x, dinv, xs2, N);
    fill_ranged<<<gR, 256, 0, stream>>>(src, dst, cursorq, csr, E, N, echunk, q1);

    // --- Layer 1: agg pre-scaled [N,2], gemm 2->128 (+b1, relu, *dinv) ---
    agg2_kernel<<<gN, 256, 0, stream>>>(xs2, off, csr, dinv, t2, N);
    gemm_small<2, 128, true, true><<<cdiv(N, 8), 256, 0, stream>>>(t2, W1, b1, dinv, bufA, N);
    // --- Layer 2: gemm 128->128 (raw, cm16 out), agg128x2 (+b2, relu, *dinv) ---
    gemm_tiled<128, 128, false, false, 0, 16><<<gT, 256, 0, stream>>>(bufA, W2, nullptr, nullptr, bufB, N);
    agg128x2_kernel<true, true><<<gX2, 256, 0, stream>>>(bufB, off, csr, dinv, b2, bufA, N);
    // --- Layer 3: gemm 128->32 (cm16 in), agg32mm (+b3, relu, *dinv, @W4) ---
    gemm_tiled<128, 32, false, false, 16, 0><<<gT, 256, 0, stream>>>(bufA, W3, nullptr, nullptr, bufB, N);
    agg32mm_kernel<<<gA, 256, 0, stream>>>(bufB, off, csr, dinv, b3, W4, bufA, N);
    // --- Layer 4: agg32 (+b4, relu, *dinv) -> D.x4 ---
    agg32_kernel<true, true><<<gA, 256, 0, stream>>>(bufA, off, csr, dinv, b4, bufB, N);
    // --- Layer 5: fused raw agg + (t@W5+b5).relu @ Wl + bl -> out ---
    agg32fin_kernel<<<gA, 256, 0, stream>>>(bufB, off, csr, dinv, W5, b5, Wl, bl, (float*)d_out, N);
}

// Round 10
// 519.985 us; speedup vs baseline: 1.0376x; 1.0376x over previous
//
#include <hip/hip_runtime.h>
#include <math.h>

// ---------------------------------------------------------------------------
// GCN 5-layer forward, dinv-prescaled formulation.
//   agg[v] = dinv[v] * ( sum_{s in N(v)} hs[s] + hs[v] ),  hs = dinv (.) h.
// Layer plan (narrow-side aggregation; D(XW)=(DX)W commuting):
//   L1: agg2(xs=dinv*x) -> gemm 2->128 +b1 relu *dinv
//   L2: gemm 128->128 (cm32 out) ; agg128x +b2 relu *dinv (cm32)
//   L3: gemm 128->32 (cm32 in) ; agg32mm: agg +b3 relu *dinv THEN @W4 fused
//   L4: agg32 +b4 relu *dinv
//   L5: agg32fin: raw agg THEN (@W5+b5).relu@Wl+bl fused -> out
// R23: REVERT R22 + de-quartile CSR build.
//   R22 post-mortem: 16-col chunks (64B granule) on 128B fetch lines = 2x
//   line under-utilization on misses; FETCH 327->415MB, dur 98.6->125us.
//   LESSON: random-gather chunk width must equal the 128B line (32 cols).
//   At 128B granule the slice is 12.8MB > L2 — agg128x's ~98us/327MB is the
//   structural floor absent a sync-free phase mechanism (family closed).
//   Quartile bucketing was null for agg (R16) and only served the closed
//   barrier family -> restored plain cnt/cursor build (saves 1.2MB zero,
//   int4->int scans, 3 compares/edge in count+fill). Predicted ~503-508us.
// R21 (511.5us): fused gemm_L4 into agg32mm + gemm_final into agg32fin.
// R20/R19/R18/R17: persistent phase-barrier family CLOSED (3 strikes;
//   FETCH 167MB proved quartile-sweep locality but sync cost ate it).
// R16 (526us): quartile edge order alone = null. R15 (REVERTED): chunking
//   on latency-bound agg32 = 4x instrs. R14: XCD-sliced cm32 agg128
//   127->98us, FETCH 414->328 (12.8MB slice > L2, hit ~63%).
// Structural walls (measured): agg128x ~98us (128B-granule random-gather
//   wall, 3.9TB/s); agg32 ~45us each (latency-bound, invariant across wave
//   shapes); fill/count atomic floors; fp32 vector-ALU gemms (no fp32 MFMA;
//   plain bf16 blows the 7.9e-5 absmax budget).
// ---------------------------------------------------------------------------

static inline int cdiv(int a, int b) { return (a + b - 1) / b; }

__global__ void zero_i32(int* __restrict__ p, int n) {
    int i = blockIdx.x * 256 + threadIdx.x;
    if (i < n) p[i] = 0;
}

// Plain 1-pass degree count: atomics, no line-ownership migration.
__global__ void count_kernel(const int* __restrict__ dst, int* __restrict__ cnt, int E) {
    int e = blockIdx.x * 256 + threadIdx.x;
    if (e < E) atomicAdd(&cnt[dst[e]], 1);
}

// Inclusive scan per 256-block; inclusive partials to off, block totals to bsum.
__global__ void scan1(const int* __restrict__ cnt, int* __restrict__ off,
                      int* __restrict__ bsum, int n) {
    __shared__ int sm[256];
    int i = blockIdx.x * 256 + threadIdx.x;
    int v = (i < n) ? cnt[i] : 0;
    sm[threadIdx.x] = v;
    __syncthreads();
    for (int ofs = 1; ofs < 256; ofs <<= 1) {
        int t = (threadIdx.x >= (unsigned)ofs) ? sm[threadIdx.x - ofs] : 0;
        __syncthreads();
        sm[threadIdx.x] += t;
        __syncthreads();
    }
    if (i < n) off[i] = sm[threadIdx.x];
    if (threadIdx.x == 255) bsum[blockIdx.x] = sm[255];
}

// Exclusive scan of block sums (nb <= 512).
__global__ void scan2(const int* __restrict__ bsum, int* __restrict__ bpre,
                      int nb, int* __restrict__ off, int N, int E) {
    __shared__ int sm[512];
    int t = threadIdx.x;
    sm[t] = (t < nb) ? bsum[t] : 0;
    __syncthreads();
    for (int ofs = 1; ofs < 512; ofs <<= 1) {
        int v = (t >= ofs) ? sm[t - ofs] : 0;
        __syncthreads();
        sm[t] += v;
        __syncthreads();
    }
    if (t < nb) bpre[t] = sm[t] - bsum[t];
    if (t == 0) off[N] = E;
}

// Fused: finalize off (exclusive), seed cursor=off, dinv=1/sqrt(deg+1),
// xs = dinv * x (pre-scaled layer-1 input).
__global__ void scan3_fused(const int* __restrict__ cnt, const int* __restrict__ bpre,
                            int* __restrict__ off, int* __restrict__ cursor,
                            const float* __restrict__ x, float* __restrict__ dinv,
                            float* __restrict__ xs, int n) {
    int i = blockIdx.x * 256 + threadIdx.x;
    if (i < n) {
        int c = cnt[i];
        int o = off[i] - c + bpre[blockIdx.x];
        off[i] = o;
        cursor[i] = o;
        float dv = 1.0f / sqrtf((float)c + 1.0f);
        dinv[i] = dv;
        float2 xv = *reinterpret_cast<const float2*>(x + 2 * (size_t)i);
        *reinterpret_cast<float2*>(xs + 2 * (size_t)i) = float2{dv * xv.x, dv * xv.y};
    }
}

// XCD-class-filtered CSR fill: class c handles only its dst-range, so its
// cursor slice (~50 KB) and csr slice (~800 KB) stay in one XCD's L2.
__global__ __launch_bounds__(256) void fill_ranged(const int* __restrict__ src,
                                                   const int* __restrict__ dst,
                                                   int* __restrict__ cursor,
                                                   int* __restrict__ csr,
                                                   int E, int N, int echunk) {
    int cls = blockIdx.x & 7;
    int chunk = blockIdx.x >> 3;
    int per = (N + 7) >> 3;
    int lo = cls * per;
    int hi = lo + per; if (hi > N) hi = N;
    int e0 = chunk * echunk;
    int e1 = e0 + echunk; if (e1 > E) e1 = E;
    for (int e = e0 + (int)threadIdx.x; e < e1; e += 256) {
        int d = dst[e];
        if (d >= lo && d < hi) {
            int p = atomicAdd(&cursor[d], 1);
            csr[p] = src[e];
        }
    }
}

// ---------------------------------------------------------------------------
// Aggregation of pre-scaled [N,2] input: one thread per node.
// ---------------------------------------------------------------------------
__global__ __launch_bounds__(256) void agg2_kernel(const float* __restrict__ xs,
                                                   const int* __restrict__ off,
                                                   const int* __restrict__ csr,
                                                   const float* __restrict__ dinv,
                                                   float* __restrict__ out, int n) {
    int v = blockIdx.x * 256 + threadIdx.x;
    if (v >= n) return;
    float a0 = 0.f, a1 = 0.f;
    int e0 = off[v], e1 = off[v + 1];
    for (int e = e0; e < e1; e++) {
        int s = csr[e];
        float2 q = *reinterpret_cast<const float2*>(xs + 2 * (size_t)s);
        a0 += q.x;
        a1 += q.y;
    }
    float dv = dinv[v];
    float2 xv = *reinterpret_cast<const float2*>(xs + 2 * (size_t)v);
    *reinterpret_cast<float2*>(out + 2 * (size_t)v) =
        float2{dv * (a0 + xv.x), dv * (a1 + xv.y)};
}

// ---------------------------------------------------------------------------
// agg128x: F=128 aggregation, XCD-sliced. h is chunk-major hc[4][N][32].
// class = blockIdx&7: chunk = cls>>1 (32-col slice = one 128B line/node),
// half = cls&1 (dst half). 12.8MB slice per XCD; 128B granule per edge.
// ---------------------------------------------------------------------------
template <bool BR, bool PS>
__global__ __launch_bounds__(256) void agg128x_kernel(const float* __restrict__ hc,
                                                      const int* __restrict__ off,
                                                      const int* __restrict__ csr,
                                                      const float* __restrict__ dinv,
                                                      const float* __restrict__ bias,
                                                      float* __restrict__ outc, int n) {
    int cls = blockIdx.x & 7;
    int chunk = cls >> 1;
    int half = cls & 1;
    int n2 = (n + 1) >> 1;
    int lo = half * n2;
    int hi = lo + n2; if (hi > n) hi = n;

    const float* __restrict__ h = hc + (size_t)chunk * n * 32;
    float* __restrict__ out = outc + (size_t)chunk * n * 32;

    int tid = threadIdx.x;
    int lane = tid & 63;
    int sl = lane & 7;
    int subbase = lane & ~7;
    int wave = tid >> 6;
    int v = lo + (blockIdx.x >> 3) * 32 + wave * 8 + (lane >> 3);
    if (v >= hi) return;

    int start = off[v];
    int end = off[v + 1];

    float4 acc = {0.f, 0.f, 0.f, 0.f};

    for (int base = start; base < end; base += 16) {
        int m = end - base;
        if (m > 16) m = 16;
        int idxA = (sl < m) ? csr[base + sl] : 0;
        int idxB = (8 + sl < m) ? csr[base + 8 + sl] : 0;
        if (m == 16) {
            float4 hb[16];
#pragma unroll
            for (int u = 0; u < 16; u++) {
                int s = __shfl((u < 8) ? idxA : idxB, subbase + (u & 7));
                hb[u] = *reinterpret_cast<const float4*>(h + (size_t)s * 32 + sl * 4);
            }
#pragma unroll
            for (int u = 0; u < 16; u++) {
                acc.x += hb[u].x; acc.y += hb[u].y; acc.z += hb[u].z; acc.w += hb[u].w;
            }
        } else {
            int ma = (m < 8) ? m : 8;
            int i = 0;
            for (; i + 4 <= ma; i += 4) {
                float4 hb[4];
#pragma unroll
                for (int u = 0; u < 4; u++) {
                    int s = __shfl(idxA, subbase + i + u);
                    hb[u] = *reinterpret_cast<const float4*>(h + (size_t)s * 32 + sl * 4);
                }
#pragma unroll
                for (int u = 0; u < 4; u++) {
                    acc.x += hb[u].x; acc.y += hb[u].y; acc.z += hb[u].z; acc.w += hb[u].w;
                }
            }
            if (i + 2 <= ma) {
                int s0 = __shfl(idxA, subbase + i);
                int s1 = __shfl(idxA, subbase + i + 1);
                float4 h0 = *reinterpret_cast<const float4*>(h + (size_t)s0 * 32 + sl * 4);
                float4 h1 = *reinterpret_cast<const float4*>(h + (size_t)s1 * 32 + sl * 4);
                acc.x += h0.x + h1.x; acc.y += h0.y + h1.y;
                acc.z += h0.z + h1.z; acc.w += h0.w + h1.w;
                i += 2;
            }
            if (i < ma) {
                int s0 = __shfl(idxA, subbase + i);
                float4 h0 = *reinterpret_cast<const float4*>(h + (size_t)s0 * 32 + sl * 4);
                acc.x += h0.x; acc.y += h0.y; acc.z += h0.z; acc.w += h0.w;
            }
            if (m > 8) {
                int mb = m - 8;
                int j = 0;
                for (; j + 4 <= mb; j += 4) {
                    float4 hb[4];
#pragma unroll
                    for (int u = 0; u < 4; u++) {
                        int s = __shfl(idxB, subbase + j + u);
                        hb[u] = *reinterpret_cast<const float4*>(h + (size_t)s * 32 + sl * 4);
                    }
#pragma unroll
                    for (int u = 0; u < 4; u++) {
                        acc.x += hb[u].x; acc.y += hb[u].y; acc.z += hb[u].z; acc.w += hb[u].w;
                    }
                }
                if (j + 2 <= mb) {
                    int s0 = __shfl(idxB, subbase + j);
                    int s1 = __shfl(idxB, subbase + j + 1);
                    float4 h0 = *reinterpret_cast<const float4*>(h + (size_t)s0 * 32 + sl * 4);
                    float4 h1 = *reinterpret_cast<const float4*>(h + (size_t)s1 * 32 + sl * 4);
                    acc.x += h0.x + h1.x; acc.y += h0.y + h1.y;
                    acc.z += h0.z + h1.z; acc.w += h0.w + h1.w;
                    j += 2;
                }
                if (j < mb) {
                    int s0 = __shfl(idxB, subbase + j);
                    float4 h0 = *reinterpret_cast<const float4*>(h + (size_t)s0 * 32 + sl * 4);
                    acc.x += h0.x; acc.y += h0.y; acc.z += h0.z; acc.w += h0.w;
                }
            }
        }
    }

    float dv = dinv[v];
    float4 hv = *reinterpret_cast<const float4*>(h + (size_t)v * 32 + sl * 4);
    float o0 = dv * (acc.x + hv.x);
    float o1 = dv * (acc.y + hv.y);
    float o2 = dv * (acc.z + hv.z);
    float o3 = dv * (acc.w + hv.w);
    if constexpr (BR) {
        float4 b = *reinterpret_cast<const float4*>(bias + chunk * 32 + sl * 4);
        o0 = fmaxf(o0 + b.x, 0.f);
        o1 = fmaxf(o1 + b.y, 0.f);
        o2 = fmaxf(o2 + b.z, 0.f);
        o3 = fmaxf(o3 + b.w, 0.f);
    }
    if constexpr (PS) {
        o0 *= dv; o1 *= dv; o2 *= dv; o3 *= dv;
    }
    *reinterpret_cast<float4*>(out + (size_t)v * 32 + sl * 4) = float4{o0, o1, o2, o3};
}

// ---------------------------------------------------------------------------
// Shared agg32 gather body: 8 lanes/node, lane owns 4 cols. Returns acc.
// ---------------------------------------------------------------------------
__device__ __forceinline__ float4 agg32_gather(const float* __restrict__ h,
                                               const int* __restrict__ csr,
                                               int start, int end,
                                               int sl, int subbase) {
    float4 acc = {0.f, 0.f, 0.f, 0.f};
    for (int base = start; base < end; base += 16) {
        int m = end - base;
        if (m > 16) m = 16;
        int idxA = (sl < m) ? csr[base + sl] : 0;
        int idxB = (8 + sl < m) ? csr[base + 8 + sl] : 0;
        if (m == 16) {
            float4 hb[16];
#pragma unroll
            for (int u = 0; u < 16; u++) {
                int s = __shfl((u < 8) ? idxA : idxB, subbase + (u & 7));
                hb[u] = *reinterpret_cast<const float4*>(h + (size_t)s * 32 + sl * 4);
            }
#pragma unroll
            for (int u = 0; u < 16; u++) {
                acc.x += hb[u].x; acc.y += hb[u].y; acc.z += hb[u].z; acc.w += hb[u].w;
            }
        } else {
            int ma = (m < 8) ? m : 8;
            int i = 0;
            for (; i + 4 <= ma; i += 4) {
                float4 hb[4];
#pragma unroll
                for (int u = 0; u < 4; u++) {
                    int s = __shfl(idxA, subbase + i + u);
                    hb[u] = *reinterpret_cast<const float4*>(h + (size_t)s * 32 + sl * 4);
                }
#pragma unroll
                for (int u = 0; u < 4; u++) {
                    acc.x += hb[u].x; acc.y += hb[u].y; acc.z += hb[u].z; acc.w += hb[u].w;
                }
            }
            if (i + 2 <= ma) {
                int s0 = __shfl(idxA, subbase + i);
                int s1 = __shfl(idxA, subbase + i + 1);
                float4 h0 = *reinterpret_cast<const float4*>(h + (size_t)s0 * 32 + sl * 4);
                float4 h1 = *reinterpret_cast<const float4*>(h + (size_t)s1 * 32 + sl * 4);
                acc.x += h0.x + h1.x; acc.y += h0.y + h1.y;
                acc.z += h0.z + h1.z; acc.w += h0.w + h1.w;
                i += 2;
            }
            if (i < ma) {
                int s0 = __shfl(idxA, subbase + i);
                float4 h0 = *reinterpret_cast<const float4*>(h + (size_t)s0 * 32 + sl * 4);
                acc.x += h0.x; acc.y += h0.y; acc.z += h0.z; acc.w += h0.w;
            }
            if (m > 8) {
                int mb = m - 8;
                int j = 0;
                for (; j + 4 <= mb; j += 4) {
                    float4 hb[4];
#pragma unroll
                    for (int u = 0; u < 4; u++) {
                        int s = __shfl(idxB, subbase + j + u);
                        hb[u] = *reinterpret_cast<const float4*>(h + (size_t)s * 32 + sl * 4);
                    }
#pragma unroll
                    for (int u = 0; u < 4; u++) {
                        acc.x += hb[u].x; acc.y += hb[u].y; acc.z += hb[u].z; acc.w += hb[u].w;
                    }
                }
                if (j + 2 <= mb) {
                    int s0 = __shfl(idxB, subbase + j);
                    int s1 = __shfl(idxB, subbase + j + 1);
                    float4 h0 = *reinterpret_cast<const float4*>(h + (size_t)s0 * 32 + sl * 4);
                    float4 h1 = *reinterpret_cast<const float4*>(h + (size_t)s1 * 32 + sl * 4);
                    acc.x += h0.x + h1.x; acc.y += h0.y + h1.y;
                    acc.z += h0.z + h1.z; acc.w += h0.w + h1.w;
                    j += 2;
                }
                if (j < mb) {
                    int s0 = __shfl(idxB, subbase + j);
                    float4 h0 = *reinterpret_cast<const float4*>(h + (size_t)s0 * 32 + sl * 4);
                    acc.x += h0.x; acc.y += h0.y; acc.z += h0.z; acc.w += h0.w;
                }
            }
        }
    }
    return acc;
}

// ---------------------------------------------------------------------------
// agg32: plain F=32 aggregation (+bias/relu BR, post-scale PS).
// ---------------------------------------------------------------------------
template <bool BR, bool PS>
__global__ __launch_bounds__(256) void agg32_kernel(const float* __restrict__ h,
                                                    const int* __restrict__ off,
                                                    const int* __restrict__ csr,
                                                    const float* __restrict__ dinv,
                                                    const float* __restrict__ bias,
                                                    float* __restrict__ out, int n) {
    int tid = threadIdx.x;
    int lane = tid & 63;
    int sl = lane & 7;
    int subbase = lane & ~7;
    int wave = tid >> 6;
    int v = blockIdx.x * 32 + wave * 8 + (lane >> 3);
    if (v >= n) return;

    float4 acc = agg32_gather(h, csr, off[v], off[v + 1], sl, subbase);

    float dv = dinv[v];
    float4 hv = *reinterpret_cast<const float4*>(h + (size_t)v * 32 + sl * 4);
    float o0 = dv * (acc.x + hv.x);
    float o1 = dv * (acc.y + hv.y);
    float o2 = dv * (acc.z + hv.z);
    float o3 = dv * (acc.w + hv.w);
    if constexpr (BR) {
        float4 b = *reinterpret_cast<const float4*>(bias + sl * 4);
        o0 = fmaxf(o0 + b.x, 0.f);
        o1 = fmaxf(o1 + b.y, 0.f);
        o2 = fmaxf(o2 + b.z, 0.f);
        o3 = fmaxf(o3 + b.w, 0.f);
    }
    if constexpr (PS) {
        o0 *= dv; o1 *= dv; o2 *= dv; o3 *= dv;
    }
    *reinterpret_cast<float4*>(out + (size_t)v * 32 + sl * 4) = float4{o0, o1, o2, o3};
}

// ---------------------------------------------------------------------------
// agg32mm: agg32 (+b, relu, *dv) FUSED with @W (32x32) -> out = (D.x3)@W4.
// W staged in 4KB LDS; per node: 32 shfl broadcasts + 32 float4 FMAs,
// hidden under the latency-bound gather. Output row-major [N][32].
// ---------------------------------------------------------------------------
__global__ __launch_bounds__(256) void agg32mm_kernel(const float* __restrict__ h,
                                                      const int* __restrict__ off,
                                                      const int* __restrict__ csr,
                                                      const float* __restrict__ dinv,
                                                      const float* __restrict__ bias,
                                                      const float* __restrict__ W,
                                                      float* __restrict__ out, int n) {
    __shared__ float Ws[32 * 32];
    int tid = threadIdx.x;
    *reinterpret_cast<float4*>(&Ws[tid * 4]) =
        *reinterpret_cast<const float4*>(W + tid * 4);
    __syncthreads();

    int lane = tid & 63;
    int sl = lane & 7;
    int subbase = lane & ~7;
    int wave = tid >> 6;
    int v = blockIdx.x * 32 + wave * 8 + (lane >> 3);
    if (v >= n) return;

    float4 acc = agg32_gather(h, csr, off[v], off[v + 1], sl, subbase);

    float dv = dinv[v];
    float4 hv = *reinterpret_cast<const float4*>(h + (size_t)v * 32 + sl * 4);
    float4 b = *reinterpret_cast<const float4*>(bias + sl * 4);
    float o0 = fmaxf(dv * (acc.x + hv.x) + b.x, 0.f) * dv;
    float o1 = fmaxf(dv * (acc.y + hv.y) + b.y, 0.f) * dv;
    float o2 = fmaxf(dv * (acc.z + hv.z) + b.z, 0.f) * dv;
    float o3 = fmaxf(dv * (acc.w + hv.w) + b.w, 0.f) * dv;

    // y[4sl..4sl+3] = sum_k x[k] * W[k][4sl..]; x[k] broadcast via shfl.
    float y0 = 0.f, y1 = 0.f, y2 = 0.f, y3 = 0.f;
#pragma unroll
    for (int q = 0; q < 8; q++) {
        float x0 = __shfl(o0, subbase + q);
        float x1 = __shfl(o1, subbase + q);
        float x2 = __shfl(o2, subbase + q);
        float x3 = __shfl(o3, subbase + q);
        float4 w0 = *reinterpret_cast<const float4*>(&Ws[(4 * q + 0) * 32 + sl * 4]);
        float4 w1 = *reinterpret_cast<const float4*>(&Ws[(4 * q + 1) * 32 + sl * 4]);
        float4 w2 = *reinterpret_cast<const float4*>(&Ws[(4 * q + 2) * 32 + sl * 4]);
        float4 w3 = *reinterpret_cast<const float4*>(&Ws[(4 * q + 3) * 32 + sl * 4]);
        y0 += x0 * w0.x + x1 * w1.x + x2 * w2.x + x3 * w3.x;
        y1 += x0 * w0.y + x1 * w1.y + x2 * w2.y + x3 * w3.y;
        y2 += x0 * w0.z + x1 * w1.z + x2 * w2.z + x3 * w3.z;
        y3 += x0 * w0.w + x1 * w1.w + x2 * w2.w + x3 * w3.w;
    }
    *reinterpret_cast<float4*>(out + (size_t)v * 32 + sl * 4) = float4{y0, y1, y2, y3};
}

// ---------------------------------------------------------------------------
// agg32fin: raw agg32 FUSED with (t@W5+b5).relu @ Wl + bl -> out[v] scalar.
// W5 (8KB), b5, wl staged in LDS; lane owns 8 of 64 mid-cols; 8-lane
// shfl-xor reduce; lane0-of-8 writes.
// ---------------------------------------------------------------------------
__global__ __launch_bounds__(256) void agg32fin_kernel(const float* __restrict__ h,
                                                       const int* __restrict__ off,
                                                       const int* __restrict__ csr,
                                                       const float* __restrict__ dinv,
                                                       const float* __restrict__ W5,
                                                       const float* __restrict__ b5,
                                                       const float* __restrict__ Wl,
                                                       const float* __restrict__ bl,
                                                       float* __restrict__ out, int n) {
    __shared__ float W5s[32 * 64];
    __shared__ float b5s[64];
    __shared__ float wls[64];
    int tid = threadIdx.x;
    *reinterpret_cast<float4*>(&W5s[tid * 8]) =
        *reinterpret_cast<const float4*>(W5 + tid * 8);
    *reinterpret_cast<float4*>(&W5s[tid * 8 + 4]) =
        *reinterpret_cast<const float4*>(W5 + tid * 8 + 4);
    if (tid < 64) b5s[tid] = b5[tid];
    else if (tid < 128) wls[tid - 64] = Wl[tid - 64];
    __syncthreads();

    int lane = tid & 63;
    int sl = lane & 7;
    int subbase = lane & ~7;
    int wave = tid >> 6;
    int v = blockIdx.x * 32 + wave * 8 + (lane >> 3);
    if (v >= n) return;

    float4 acc = agg32_gather(h, csr, off[v], off[v + 1], sl, subbase);

    float dv = dinv[v];
    float4 hv = *reinterpret_cast<const float4*>(h + (size_t)v * 32 + sl * 4);
    float t0 = dv * (acc.x + hv.x);
    float t1 = dv * (acc.y + hv.y);
    float t2 = dv * (acc.z + hv.z);
    float t3 = dv * (acc.w + hv.w);

    // y[sl*8 .. sl*8+7] = sum_k t[k] * W5[k][sl*8..]
    float y0 = 0.f, y1 = 0.f, y2 = 0.f, y3 = 0.f;
    float y4 = 0.f, y5 = 0.f, y6 = 0.f, y7 = 0.f;
#pragma unroll
    for (int q = 0; q < 8; q++) {
        float x0 = __shfl(t0, subbase + q);
        float x1 = __shfl(t1, subbase + q);
        float x2 = __shfl(t2, subbase + q);
        float x3 = __shfl(t3, subbase + q);
#pragma unroll
        for (int r = 0; r < 4; r++) {
            float xv = (r == 0) ? x0 : (r == 1) ? x1 : (r == 2) ? x2 : x3;
            const float* wr = &W5s[(4 * q + r) * 64 + sl * 8];
            float4 wa = *reinterpret_cast<const float4*>(wr);
            float4 wb = *reinterpret_cast<const float4*>(wr + 4);
            y0 += xv * wa.x; y1 += xv * wa.y; y2 += xv * wa.z; y3 += xv * wa.w;
            y4 += xv * wb.x; y5 += xv * wb.y; y6 += xv * wb.z; y7 += xv * wb.w;
        }
    }
    float4 ba = *reinterpret_cast<const float4*>(&b5s[sl * 8]);
    float4 bb = *reinterpret_cast<const float4*>(&b5s[sl * 8 + 4]);
    float4 wa = *reinterpret_cast<const float4*>(&wls[sl * 8]);
    float4 wb = *reinterpret_cast<const float4*>(&wls[sl * 8 + 4]);
    float z = fmaxf(y0 + ba.x, 0.f) * wa.x + fmaxf(y1 + ba.y, 0.f) * wa.y +
              fmaxf(y2 + ba.z, 0.f) * wa.z + fmaxf(y3 + ba.w, 0.f) * wa.w +
              fmaxf(y4 + bb.x, 0.f) * wb.x + fmaxf(y5 + bb.y, 0.f) * wb.y +
              fmaxf(y6 + bb.z, 0.f) * wb.z + fmaxf(y7 + bb.w, 0.f) * wb.w;
    z += __shfl_xor(z, 4);
    z += __shfl_xor(z, 2);
    z += __shfl_xor(z, 1);
    if (sl == 0) out[v] = z + bl[0];
}

// ---------------------------------------------------------------------------
// Register-tiled GEMM: h[N,F] = x[N,K] @ W[K,F]; epilogue +bias/relu (BR),
// *dinv[row] (PS). KC=32 (KCP=36 breaks pow-2 banks).
// CIN/COUT: 0 = row-major, 32 = chunk-major [F/32][N][32] (for agg128x).
// ---------------------------------------------------------------------------
template <int K, int F, bool BR, bool PS, int CIN = 0, int COUT = 0>
__global__ __launch_bounds__(256, 4) void gemm_tiled(const float* __restrict__ x,
                                                     const float* __restrict__ W,
                                                     const float* __restrict__ bias,
                                                     const float* __restrict__ dinv,
                                                     float* __restrict__ h, int n) {
    constexpr int KC = 32;
    constexpr int KCP = 36;             // padded row stride (144 B, 16B-aligned)
    constexpr int ROWS = 64;
    constexpr int TPC = F / 4;
    constexpr int RT = 256 / TPC;
    constexpr int RPT = ROWS / RT;
    static_assert(K % KC == 0, "K must be a multiple of 32");

    __shared__ float Ws[KC * F];
    __shared__ float Xs[ROWS * KCP];

    const int tid = threadIdx.x;
    const int cb = (tid % TPC) * 4;
    const int tr = tid / TPC;
    const int row0 = blockIdx.x * ROWS;

    float acc[RPT][4];
#pragma unroll
    for (int r = 0; r < RPT; r++)
#pragma unroll
        for (int j = 0; j < 4; j++) acc[r][j] = 0.f;

#pragma unroll 1
    for (int k0 = 0; k0 < K; k0 += KC) {
        __syncthreads();
        {
            int r = tid >> 2;
            int kk = (tid & 3) * 8;
            int gr = row0 + r;
            float4 v0 = {0.f, 0.f, 0.f, 0.f}, v1 = {0.f, 0.f, 0.f, 0.f};
            if (gr < n) {
                if constexpr (CIN == 32) {
                    const float* xb = x + (size_t)(k0 >> 5) * n * 32 + (size_t)gr * 32 + kk;
                    v0 = *reinterpret_cast<const float4*>(xb);
                    v1 = *reinterpret_cast<const float4*>(xb + 4);
                } else {
                    v0 = *reinterpret_cast<const float4*>(x + (size_t)gr * K + k0 + kk);
                    v1 = *reinterpret_cast<const float4*>(x + (size_t)gr * K + k0 + kk + 4);
                }
            }
            *reinterpret_cast<float4*>(&Xs[r * KCP + kk]) = v0;
            *reinterpret_cast<float4*>(&Xs[r * KCP + kk + 4]) = v1;
        }
        for (int i = tid; i < KC * F / 4; i += 256) {
            *reinterpret_cast<float4*>(&Ws[i * 4]) =
                *reinterpret_cast<const float4*>(W + (size_t)k0 * F + i * 4);
        }
        __syncthreads();

#pragma unroll 4
        for (int kk4 = 0; kk4 < KC; kk4 += 4) {
            float4 xr[RPT];
#pragma unroll
            for (int r = 0; r < RPT; r++)
                xr[r] = *reinterpret_cast<const float4*>(&Xs[(tr * RPT + r) * KCP + kk4]);
#pragma unroll
            for (int j = 0; j < 4; j++) {
                float4 w = *reinterpret_cast<const float4*>(&Ws[(kk4 + j) * F + cb]);
#pragma unroll
                for (int r = 0; r < RPT; r++) {
                    float xv = (j == 0) ? xr[r].x : (j == 1) ? xr[r].y
                             : (j == 2) ? xr[r].z : xr[r].w;
                    acc[r][0] += xv * w.x;
                    acc[r][1] += xv * w.y;
                    acc[r][2] += xv * w.z;
                    acc[r][3] += xv * w.w;
                }
            }
        }
    }

    float4 b = float4{0.f, 0.f, 0.f, 0.f};
    if constexpr (BR) b = *reinterpret_cast<const float4*>(bias + cb);
#pragma unroll
    for (int r = 0; r < RPT; r++) {
        int row = row0 + tr * RPT + r;
        if (row < n) {
            float o0 = acc[r][0], o1 = acc[r][1], o2 = acc[r][2], o3 = acc[r][3];
            if constexpr (BR) {
                o0 = fmaxf(o0 + b.x, 0.f);
                o1 = fmaxf(o1 + b.y, 0.f);
                o2 = fmaxf(o2 + b.z, 0.f);
                o3 = fmaxf(o3 + b.w, 0.f);
            }
            if constexpr (PS) {
                float dv = dinv[row];
                o0 *= dv; o1 *= dv; o2 *= dv; o3 *= dv;
            }
            if constexpr (COUT == 32) {
                float* hb = h + (size_t)(cb >> 5) * n * 32 + (size_t)row * 32 + (cb & 31);
                *reinterpret_cast<float4*>(hb) = float4{o0, o1, o2, o3};
            } else {
                *reinterpret_cast<float4*>(&h[(size_t)row * F + cb]) = float4{o0, o1, o2, o3};
            }
        }
    }
}

// Simple GEMM for K=2 (layer 1), epilogue +bias/relu (BR), *dinv (PS).
template <int K, int F, bool BR, bool PS>
__global__ __launch_bounds__(256, 4) void gemm_small(const float* __restrict__ x,
                                                     const float* __restrict__ W,
                                                     const float* __restrict__ bias,
                                                     const float* __restrict__ dinv,
                                                     float* __restrict__ h, int n) {
    constexpr int TPR = F / 4;
    constexpr int ROWS = 256 / TPR;
    __shared__ float Ws[K * F];
    for (int i = threadIdx.x; i < K * F; i += 256) Ws[i] = W[i];
    __syncthreads();

    int tid = threadIdx.x;
    int cb = (tid % TPR) * 4;
    int r = blockIdx.x * ROWS + tid / TPR;
    if (r >= n) return;

    const float* xr = x + (size_t)r * K;
    float a0 = 0.f, a1 = 0.f, a2 = 0.f, a3 = 0.f;
#pragma unroll
    for (int k = 0; k < K; k++) {
        float xv = xr[k];
        float4 w = *reinterpret_cast<const float4*>(&Ws[k * F + cb]);
        a0 += xv * w.x; a1 += xv * w.y; a2 += xv * w.z; a3 += xv * w.w;
    }
    if constexpr (BR) {
        float4 b = *reinterpret_cast<const float4*>(bias + cb);
        a0 = fmaxf(a0 + b.x, 0.f);
        a1 = fmaxf(a1 + b.y, 0.f);
        a2 = fmaxf(a2 + b.z, 0.f);
        a3 = fmaxf(a3 + b.w, 0.f);
    }
    if constexpr (PS) {
        float dv = dinv[r];
        a0 *= dv; a1 *= dv; a2 *= dv; a3 *= dv;
    }
    *reinterpret_cast<float4*>(&h[(size_t)r * F + cb]) = float4{a0, a1, a2, a3};
}

extern "C" void kernel_launch(void* const* d_in, const int* in_sizes, int n_in,
                              void* d_out, int out_size, void* d_ws, size_t ws_size,
                              hipStream_t stream) {
    const float* x = (const float*)d_in[0];
    const int* ei = (const int*)d_in[1];
    const float* W1 = (const float*)d_in[3];
    const float* b1 = (const float*)d_in[4];
    const float* W2 = (const float*)d_in[5];
    const float* b2 = (const float*)d_in[6];
    const float* W3 = (const float*)d_in[7];
    const float* b3 = (const float*)d_in[8];
    const float* W4 = (const float*)d_in[9];
    const float* b4 = (const float*)d_in[10];
    const float* W5 = (const float*)d_in[11];
    const float* b5 = (const float*)d_in[12];
    const float* Wl = (const float*)d_in[13];
    const float* bl = (const float*)d_in[14];

    const int N = in_sizes[0] / 2;
    const int E = in_sizes[1] / 2;
    const int* src = ei;
    const int* dst = ei + E;

    char* wp = (char*)d_ws;
    auto alloc = [&](size_t bytes) -> void* {
        void* p = wp;
        wp += ((bytes + 255) / 256) * 256;
        return p;
    };
    int* cnt = (int*)alloc((size_t)N * 4);
    int* off = (int*)alloc((size_t)(N + 1) * 4);
    int* cursor = (int*)alloc((size_t)N * 4);
    int* bsum = (int*)alloc(512 * 4);
    int* bpre = (int*)alloc(512 * 4);
    int* csr = (int*)alloc((size_t)E * 4);
    float* dinv = (float*)alloc((size_t)N * 4);
    float* xs2 = (float*)alloc((size_t)N * 2 * 4);
    float* t2 = (float*)alloc((size_t)N * 2 * 4);
    float* bufA = (float*)alloc((size_t)N * 128 * 4);
    float* bufB = (float*)alloc((size_t)N * 128 * 4);

    const int gN = cdiv(N, 256);
    const int gE = cdiv(E, 256);
    const int nb = gN;
    const int gT = cdiv(N, 64);

    // Ranged fill grid: 8 classes x 128 chunks.
    const int NCHUNK = 128;
    const int echunk = cdiv(E, NCHUNK);
    const int gR = 8 * NCHUNK;

    // agg128x grid: 8 classes (4 chunks x 2 dst-halves) x node-groups of 32.
    const int gX = 8 * cdiv((N + 1) / 2, 32);
    const int gA = cdiv(N, 32);

    // --- CSR build (plain; quartile machinery removed — R16 null, barrier
    // family closed) ---
    zero_i32<<<gN, 256, 0, stream>>>(cnt, N);
    count_kernel<<<gE, 256, 0, stream>>>(dst, cnt, E);
    scan1<<<nb, 256, 0, stream>>>(cnt, off, bsum, N);
    scan2<<<1, 512, 0, stream>>>(bsum, bpre, nb, off, N, E);
    scan3_fused<<<nb, 256, 0, stream>>>(cnt, bpre, off, cursor, x, dinv, xs2, N);
    fill_ranged<<<gR, 256, 0, stream>>>(src, dst, cursor, csr, E, N, echunk);

    // --- Layer 1: agg pre-scaled [N,2], gemm 2->128 (+b1, relu, *dinv) ---
    agg2_kernel<<<gN, 256, 0, stream>>>(xs2, off, csr, dinv, t2, N);
    gemm_small<2, 128, true, true><<<cdiv(N, 8), 256, 0, stream>>>(t2, W1, b1, dinv, bufA, N);
    // --- Layer 2: gemm 128->128 (raw, cm32 out), agg128x (+b2, relu, *dinv) ---
    gemm_tiled<128, 128, false, false, 0, 32><<<gT, 256, 0, stream>>>(bufA, W2, nullptr, nullptr, bufB, N);
    agg128x_kernel<true, true><<<gX, 256, 0, stream>>>(bufB, off, csr, dinv, b2, bufA, N);
    // --- Layer 3: gemm 128->32 (cm32 in), agg32mm (+b3, relu, *dinv, @W4) ---
    gemm_tiled<128, 32, false, false, 32, 0><<<gT, 256, 0, stream>>>(bufA, W3, nullptr, nullptr, bufB, N);
    agg32mm_kernel<<<gA, 256, 0, stream>>>(bufB, off, csr, dinv, b3, W4, bufA, N);
    // --- Layer 4: agg32 (+b4, relu, *dinv) -> D.x4 ---
    agg32_kernel<true, true><<<gA, 256, 0, stream>>>(bufA, off, csr, dinv, b4, bufB, N);
    // --- Layer 5: fused raw agg + (t@W5+b5).relu @ Wl + bl -> out ---
    agg32fin_kernel<<<gA, 256, 0, stream>>>(bufB, off, csr, dinv, W5, b5, Wl, bl, (float*)d_out, N);
}

// Round 11
// 503.367 us; speedup vs baseline: 1.0719x; 1.0330x over previous
//
#include <hip/hip_runtime.h>
#include <math.h>

// ---------------------------------------------------------------------------
// GCN 5-layer forward, dinv-prescaled formulation.
//   agg[v] = dinv[v] * ( sum_{s in N(v)} hs[s] + hs[v] ),  hs = dinv (.) h.
// Layer plan (narrow-side aggregation; D(XW)=(DX)W commuting):
//   L1: agg2mm: lane-parallel agg of xs=dinv*x FUSED with gemm 2->128
//       (+b1 relu *dinv)
//   L2: gemm 128->128 (cm32 out) ; agg128x +b2 relu *dinv (cm32)
//   L3: gemm 128->32 (cm32 in) ; agg32mm: agg +b3 relu *dinv THEN @W4 fused
//   L4: agg32 +b4 relu *dinv
//   L5: agg32fin: raw agg THEN (@W5+b5).relu@Wl+bl fused -> out
// R24: restore QUARTILE build (R23 post-mortem: de-quartiling REGRESSED
//   520.0 vs R21's 511.5 with agg128x identical — the 4-way bucketed
//   count/fill atomics cut same-address contention on hot dst nodes ~4x;
//   the machinery is a win, not overhead). Plus agg2+gemm_small -> agg2mm:
//   32 lanes/row split the edge list (kills the serial 16-edge latency
//   chain), 5-step shfl_xor butterfly (masks<=16 stay in-row), per-lane
//   4-col W1 matmul from 1KB LDS. Deletes 1 dispatch + t2 round-trip.
//   Predicted total ~500-507us. Falsifier: >=511.5 -> revert to R21 exact
//   and declare roofline.
// R23 (520.0, REVERTED): plain build slower — quartile atomics win.
// R22 (539.6, REVERTED): 16-col chunks = 64B granule on 128B lines, 2x
//   miss under-utilization; FETCH 327->415MB. LESSON: random-gather chunk
//   width must equal the 128B line (32 cols); 12.8MB ws > L2 is the floor.
// R21 (511.5): fused gemm_L4 into agg32mm + gemm_final into agg32fin.
// R20..R17: persistent phase-barrier family CLOSED (spills / global-barrier
//   collapse / per-XCD barrier deadlock-to-cap; FETCH 167MB proved the
//   quartile-sweep locality but sync cost ate it).
// R16: quartile edge order alone = null for agg. R15 (REVERTED): chunking
//   on latency-bound agg32 = 4x instrs. R14: XCD-sliced cm32 agg128
//   127->98us, FETCH 414->328 (12.8MB slice > L2, hit ~63%).
// Structural walls (measured): agg128x ~98us (128B-granule random-gather
//   wall, 3.9TB/s); agg32 ~45us each (latency-bound, invariant across wave
//   shapes); fill/count atomic floors; fp32 vector-ALU gemms (no fp32 MFMA;
//   plain bf16 blows the 7.9e-5 absmax budget).
// ---------------------------------------------------------------------------

static inline int cdiv(int a, int b) { return (a + b - 1) / b; }

__global__ void zero_i32(int* __restrict__ p, int n) {
    int i = blockIdx.x * 256 + threadIdx.x;
    if (i < n) p[i] = 0;
}

// Degree count per (dst, src-quartile): atomics into cntq[4N].
// 4-way bucketing spreads hot-node atomic contention (R23 lesson).
__global__ void count_q(const int* __restrict__ src, const int* __restrict__ dst,
                        int* __restrict__ cntq, int E, int q1) {
    int e = blockIdx.x * 256 + threadIdx.x;
    if (e < E) {
        int s = src[e];
        int q = (s >= q1) + (s >= 2 * q1) + (s >= 3 * q1);
        atomicAdd(&cntq[dst[e] * 4 + q], 1);
    }
}

// Inclusive scan per 256-block of per-node TOTALS; block totals to bsum.
__global__ void scan1q(const int* __restrict__ cntq, int* __restrict__ off,
                       int* __restrict__ bsum, int n) {
    __shared__ int sm[256];
    int i = blockIdx.x * 256 + threadIdx.x;
    int v = 0;
    if (i < n) {
        int4 c = *reinterpret_cast<const int4*>(cntq + 4 * (size_t)i);
        v = c.x + c.y + c.z + c.w;
    }
    sm[threadIdx.x] = v;
    __syncthreads();
    for (int ofs = 1; ofs < 256; ofs <<= 1) {
        int t = (threadIdx.x >= (unsigned)ofs) ? sm[threadIdx.x - ofs] : 0;
        __syncthreads();
        sm[threadIdx.x] += t;
        __syncthreads();
    }
    if (i < n) off[i] = sm[threadIdx.x];
    if (threadIdx.x == 255) bsum[blockIdx.x] = sm[255];
}

// Exclusive scan of block sums (nb <= 512).
__global__ void scan2(const int* __restrict__ bsum, int* __restrict__ bpre,
                      int nb, int* __restrict__ off, int N, int E) {
    __shared__ int sm[512];
    int t = threadIdx.x;
    sm[t] = (t < nb) ? bsum[t] : 0;
    __syncthreads();
    for (int ofs = 1; ofs < 512; ofs <<= 1) {
        int v = (t >= ofs) ? sm[t - ofs] : 0;
        __syncthreads();
        sm[t] += v;
        __syncthreads();
    }
    if (t < nb) bpre[t] = sm[t] - bsum[t];
    if (t == 0) off[N] = E;
}

// Fused: finalize off (exclusive), seed 4 quartile cursors per node,
// dinv=1/sqrt(deg+1), xs = dinv * x.
__global__ void scan3_fused(const int* __restrict__ cntq, const int* __restrict__ bpre,
                            int* __restrict__ off, int* __restrict__ cursorq,
                            const float* __restrict__ x, float* __restrict__ dinv,
                            float* __restrict__ xs, int n) {
    int i = blockIdx.x * 256 + threadIdx.x;
    if (i < n) {
        int4 cq = *reinterpret_cast<const int4*>(cntq + 4 * (size_t)i);
        int c = cq.x + cq.y + cq.z + cq.w;
        int o = off[i] - c + bpre[blockIdx.x];
        off[i] = o;
        int4 cur;
        cur.x = o;
        cur.y = o + cq.x;
        cur.z = o + cq.x + cq.y;
        cur.w = o + cq.x + cq.y + cq.z;
        *reinterpret_cast<int4*>(cursorq + 4 * (size_t)i) = cur;
        float dv = 1.0f / sqrtf((float)c + 1.0f);
        dinv[i] = dv;
        float2 xv = *reinterpret_cast<const float2*>(x + 2 * (size_t)i);
        *reinterpret_cast<float2*>(xs + 2 * (size_t)i) = float2{dv * xv.x, dv * xv.y};
    }
}

// XCD-class-filtered CSR fill with src-quartile bucketing.
__global__ __launch_bounds__(256) void fill_ranged(const int* __restrict__ src,
                                                   const int* __restrict__ dst,
                                                   int* __restrict__ cursorq,
                                                   int* __restrict__ csr,
                                                   int E, int N, int echunk, int q1) {
    int cls = blockIdx.x & 7;
    int chunk = blockIdx.x >> 3;
    int per = (N + 7) >> 3;
    int lo = cls * per;
    int hi = lo + per; if (hi > N) hi = N;
    int e0 = chunk * echunk;
    int e1 = e0 + echunk; if (e1 > E) e1 = E;
    for (int e = e0 + (int)threadIdx.x; e < e1; e += 256) {
        int d = dst[e];
        if (d >= lo && d < hi) {
            int s = src[e];
            int q = (s >= q1) + (s >= 2 * q1) + (s >= 3 * q1);
            int p = atomicAdd(&cursorq[d * 4 + q], 1);
            csr[p] = s;
        }
    }
}

// ---------------------------------------------------------------------------
// agg2mm: FUSED layer-1 = agg of pre-scaled [N,2] + gemm 2->128 (+b1, relu,
// *dinv). 8 rows/block, 32 lanes/row: lanes split the edge list (1 edge/lane
// at deg 16 — no serial latency chain), 5-step shfl_xor butterfly (masks
// <=16 stay within the 32-lane row group), then each lane computes its 4 of
// 128 cols from W1 in 1KB LDS. out row-major [N][128].
// ---------------------------------------------------------------------------
__global__ __launch_bounds__(256) void agg2mm_kernel(const float* __restrict__ xs,
                                                     const int* __restrict__ off,
                                                     const int* __restrict__ csr,
                                                     const float* __restrict__ dinv,
                                                     const float* __restrict__ W1,
                                                     const float* __restrict__ b1,
                                                     float* __restrict__ out, int n) {
    __shared__ float Ws[2 * 128];
    __shared__ float bs[128];
    int tid = threadIdx.x;
    if (tid < 128) {
        Ws[tid] = W1[tid];
        Ws[128 + tid] = W1[128 + tid];
        bs[tid] = b1[tid];
    }
    __syncthreads();

    int l = tid & 31;
    int v = blockIdx.x * 8 + (tid >> 5);
    if (v >= n) return;

    float a0 = 0.f, a1 = 0.f;
    int e0 = off[v], e1 = off[v + 1];
    for (int e = e0 + l; e < e1; e += 32) {
        int s = csr[e];
        float2 q = *reinterpret_cast<const float2*>(xs + 2 * (size_t)s);
        a0 += q.x;
        a1 += q.y;
    }
    a0 += __shfl_xor(a0, 16); a1 += __shfl_xor(a1, 16);
    a0 += __shfl_xor(a0, 8);  a1 += __shfl_xor(a1, 8);
    a0 += __shfl_xor(a0, 4);  a1 += __shfl_xor(a1, 4);
    a0 += __shfl_xor(a0, 2);  a1 += __shfl_xor(a1, 2);
    a0 += __shfl_xor(a0, 1);  a1 += __shfl_xor(a1, 1);

    float dv = dinv[v];
    float2 xv = *reinterpret_cast<const float2*>(xs + 2 * (size_t)v);
    float t0 = dv * (a0 + xv.x);
    float t1 = dv * (a1 + xv.y);

    int cb = l * 4;
    float4 w0 = *reinterpret_cast<const float4*>(&Ws[cb]);
    float4 w1 = *reinterpret_cast<const float4*>(&Ws[128 + cb]);
    float4 bb = *reinterpret_cast<const float4*>(&bs[cb]);
    float o0 = fmaxf(t0 * w0.x + t1 * w1.x + bb.x, 0.f) * dv;
    float o1 = fmaxf(t0 * w0.y + t1 * w1.y + bb.y, 0.f) * dv;
    float o2 = fmaxf(t0 * w0.z + t1 * w1.z + bb.z, 0.f) * dv;
    float o3 = fmaxf(t0 * w0.w + t1 * w1.w + bb.w, 0.f) * dv;
    *reinterpret_cast<float4*>(out + (size_t)v * 128 + cb) = float4{o0, o1, o2, o3};
}

// ---------------------------------------------------------------------------
// agg128x: F=128 aggregation, XCD-sliced. h is chunk-major hc[4][N][32].
// class = blockIdx&7: chunk = cls>>1 (32-col slice = one 128B line/node),
// half = cls&1 (dst half). 12.8MB slice per XCD; 128B granule per edge.
// ---------------------------------------------------------------------------
template <bool BR, bool PS>
__global__ __launch_bounds__(256) void agg128x_kernel(const float* __restrict__ hc,
                                                      const int* __restrict__ off,
                                                      const int* __restrict__ csr,
                                                      const float* __restrict__ dinv,
                                                      const float* __restrict__ bias,
                                                      float* __restrict__ outc, int n) {
    int cls = blockIdx.x & 7;
    int chunk = cls >> 1;
    int half = cls & 1;
    int n2 = (n + 1) >> 1;
    int lo = half * n2;
    int hi = lo + n2; if (hi > n) hi = n;

    const float* __restrict__ h = hc + (size_t)chunk * n * 32;
    float* __restrict__ out = outc + (size_t)chunk * n * 32;

    int tid = threadIdx.x;
    int lane = tid & 63;
    int sl = lane & 7;
    int subbase = lane & ~7;
    int wave = tid >> 6;
    int v = lo + (blockIdx.x >> 3) * 32 + wave * 8 + (lane >> 3);
    if (v >= hi) return;

    int start = off[v];
    int end = off[v + 1];

    float4 acc = {0.f, 0.f, 0.f, 0.f};

    for (int base = start; base < end; base += 16) {
        int m = end - base;
        if (m > 16) m = 16;
        int idxA = (sl < m) ? csr[base + sl] : 0;
        int idxB = (8 + sl < m) ? csr[base + 8 + sl] : 0;
        if (m == 16) {
            float4 hb[16];
#pragma unroll
            for (int u = 0; u < 16; u++) {
                int s = __shfl((u < 8) ? idxA : idxB, subbase + (u & 7));
                hb[u] = *reinterpret_cast<const float4*>(h + (size_t)s * 32 + sl * 4);
            }
#pragma unroll
            for (int u = 0; u < 16; u++) {
                acc.x += hb[u].x; acc.y += hb[u].y; acc.z += hb[u].z; acc.w += hb[u].w;
            }
        } else {
            int ma = (m < 8) ? m : 8;
            int i = 0;
            for (; i + 4 <= ma; i += 4) {
                float4 hb[4];
#pragma unroll
                for (int u = 0; u < 4; u++) {
                    int s = __shfl(idxA, subbase + i + u);
                    hb[u] = *reinterpret_cast<const float4*>(h + (size_t)s * 32 + sl * 4);
                }
#pragma unroll
                for (int u = 0; u < 4; u++) {
                    acc.x += hb[u].x; acc.y += hb[u].y; acc.z += hb[u].z; acc.w += hb[u].w;
                }
            }
            if (i + 2 <= ma) {
                int s0 = __shfl(idxA, subbase + i);
                int s1 = __shfl(idxA, subbase + i + 1);
                float4 h0 = *reinterpret_cast<const float4*>(h + (size_t)s0 * 32 + sl * 4);
                float4 h1 = *reinterpret_cast<const float4*>(h + (size_t)s1 * 32 + sl * 4);
                acc.x += h0.x + h1.x; acc.y += h0.y + h1.y;
                acc.z += h0.z + h1.z; acc.w += h0.w + h1.w;
                i += 2;
            }
            if (i < ma) {
                int s0 = __shfl(idxA, subbase + i);
                float4 h0 = *reinterpret_cast<const float4*>(h + (size_t)s0 * 32 + sl * 4);
                acc.x += h0.x; acc.y += h0.y; acc.z += h0.z; acc.w += h0.w;
            }
            if (m > 8) {
                int mb = m - 8;
                int j = 0;
                for (; j + 4 <= mb; j += 4) {
                    float4 hb[4];
#pragma unroll
                    for (int u = 0; u < 4; u++) {
                        int s = __shfl(idxB, subbase + j + u);
                        hb[u] = *reinterpret_cast<const float4*>(h + (size_t)s * 32 + sl * 4);
                    }
#pragma unroll
                    for (int u = 0; u < 4; u++) {
                        acc.x += hb[u].x; acc.y += hb[u].y; acc.z += hb[u].z; acc.w += hb[u].w;
                    }
                }
                if (j + 2 <= mb) {
                    int s0 = __shfl(idxB, subbase + j);
                    int s1 = __shfl(idxB, subbase + j + 1);
                    float4 h0 = *reinterpret_cast<const float4*>(h + (size_t)s0 * 32 + sl * 4);
                    float4 h1 = *reinterpret_cast<const float4*>(h + (size_t)s1 * 32 + sl * 4);
                    acc.x += h0.x + h1.x; acc.y += h0.y + h1.y;
                    acc.z += h0.z + h1.z; acc.w += h0.w + h1.w;
                    j += 2;
                }
                if (j < mb) {
                    int s0 = __shfl(idxB, subbase + j);
                    float4 h0 = *reinterpret_cast<const float4*>(h + (size_t)s0 * 32 + sl * 4);
                    acc.x += h0.x; acc.y += h0.y; acc.z += h0.z; acc.w += h0.w;
                }
            }
        }
    }

    float dv = dinv[v];
    float4 hv = *reinterpret_cast<const float4*>(h + (size_t)v * 32 + sl * 4);
    float o0 = dv * (acc.x + hv.x);
    float o1 = dv * (acc.y + hv.y);
    float o2 = dv * (acc.z + hv.z);
    float o3 = dv * (acc.w + hv.w);
    if constexpr (BR) {
        float4 b = *reinterpret_cast<const float4*>(bias + chunk * 32 + sl * 4);
        o0 = fmaxf(o0 + b.x, 0.f);
        o1 = fmaxf(o1 + b.y, 0.f);
        o2 = fmaxf(o2 + b.z, 0.f);
        o3 = fmaxf(o3 + b.w, 0.f);
    }
    if constexpr (PS) {
        o0 *= dv; o1 *= dv; o2 *= dv; o3 *= dv;
    }
    *reinterpret_cast<float4*>(out + (size_t)v * 32 + sl * 4) = float4{o0, o1, o2, o3};
}

// ---------------------------------------------------------------------------
// Shared agg32 gather body: 8 lanes/node, lane owns 4 cols. Returns acc.
// ---------------------------------------------------------------------------
__device__ __forceinline__ float4 agg32_gather(const float* __restrict__ h,
                                               const int* __restrict__ csr,
                                               int start, int end,
                                               int sl, int subbase) {
    float4 acc = {0.f, 0.f, 0.f, 0.f};
    for (int base = start; base < end; base += 16) {
        int m = end - base;
        if (m > 16) m = 16;
        int idxA = (sl < m) ? csr[base + sl] : 0;
        int idxB = (8 + sl < m) ? csr[base + 8 + sl] : 0;
        if (m == 16) {
            float4 hb[16];
#pragma unroll
            for (int u = 0; u < 16; u++) {
                int s = __shfl((u < 8) ? idxA : idxB, subbase + (u & 7));
                hb[u] = *reinterpret_cast<const float4*>(h + (size_t)s * 32 + sl * 4);
            }
#pragma unroll
            for (int u = 0; u < 16; u++) {
                acc.x += hb[u].x; acc.y += hb[u].y; acc.z += hb[u].z; acc.w += hb[u].w;
            }
        } else {
            int ma = (m < 8) ? m : 8;
            int i = 0;
            for (; i + 4 <= ma; i += 4) {
                float4 hb[4];
#pragma unroll
                for (int u = 0; u < 4; u++) {
                    int s = __shfl(idxA, subbase + i + u);
                    hb[u] = *reinterpret_cast<const float4*>(h + (size_t)s * 32 + sl * 4);
                }
#pragma unroll
                for (int u = 0; u < 4; u++) {
                    acc.x += hb[u].x; acc.y += hb[u].y; acc.z += hb[u].z; acc.w += hb[u].w;
                }
            }
            if (i + 2 <= ma) {
                int s0 = __shfl(idxA, subbase + i);
                int s1 = __shfl(idxA, subbase + i + 1);
                float4 h0 = *reinterpret_cast<const float4*>(h + (size_t)s0 * 32 + sl * 4);
                float4 h1 = *reinterpret_cast<const float4*>(h + (size_t)s1 * 32 + sl * 4);
                acc.x += h0.x + h1.x; acc.y += h0.y + h1.y;
                acc.z += h0.z + h1.z; acc.w += h0.w + h1.w;
                i += 2;
            }
            if (i < ma) {
                int s0 = __shfl(idxA, subbase + i);
                float4 h0 = *reinterpret_cast<const float4*>(h + (size_t)s0 * 32 + sl * 4);
                acc.x += h0.x; acc.y += h0.y; acc.z += h0.z; acc.w += h0.w;
            }
            if (m > 8) {
                int mb = m - 8;
                int j = 0;
                for (; j + 4 <= mb; j += 4) {
                    float4 hb[4];
#pragma unroll
                    for (int u = 0; u < 4; u++) {
                        int s = __shfl(idxB, subbase + j + u);
                        hb[u] = *reinterpret_cast<const float4*>(h + (size_t)s * 32 + sl * 4);
                    }
#pragma unroll
                    for (int u = 0; u < 4; u++) {
                        acc.x += hb[u].x; acc.y += hb[u].y; acc.z += hb[u].z; acc.w += hb[u].w;
                    }
                }
                if (j + 2 <= mb) {
                    int s0 = __shfl(idxB, subbase + j);
                    int s1 = __shfl(idxB, subbase + j + 1);
                    float4 h0 = *reinterpret_cast<const float4*>(h + (size_t)s0 * 32 + sl * 4);
                    float4 h1 = *reinterpret_cast<const float4*>(h + (size_t)s1 * 32 + sl * 4);
                    acc.x += h0.x + h1.x; acc.y += h0.y + h1.y;
                    acc.z += h0.z + h1.z; acc.w += h0.w + h1.w;
                    j += 2;
                }
                if (j < mb) {
                    int s0 = __shfl(idxB, subbase + j);
                    float4 h0 = *reinterpret_cast<const float4*>(h + (size_t)s0 * 32 + sl * 4);
                    acc.x += h0.x; acc.y += h0.y; acc.z += h0.z; acc.w += h0.w;
                }
            }
        }
    }
    return acc;
}

// ---------------------------------------------------------------------------
// agg32: plain F=32 aggregation (+bias/relu BR, post-scale PS).
// ---------------------------------------------------------------------------
template <bool BR, bool PS>
__global__ __launch_bounds__(256) void agg32_kernel(const float* __restrict__ h,
                                                    const int* __restrict__ off,
                                                    const int* __restrict__ csr,
                                                    const float* __restrict__ dinv,
                                                    const float* __restrict__ bias,
                                                    float* __restrict__ out, int n) {
    int tid = threadIdx.x;
    int lane = tid & 63;
    int sl = lane & 7;
    int subbase = lane & ~7;
    int wave = tid >> 6;
    int v = blockIdx.x * 32 + wave * 8 + (lane >> 3);
    if (v >= n) return;

    float4 acc = agg32_gather(h, csr, off[v], off[v + 1], sl, subbase);

    float dv = dinv[v];
    float4 hv = *reinterpret_cast<const float4*>(h + (size_t)v * 32 + sl * 4);
    float o0 = dv * (acc.x + hv.x);
    float o1 = dv * (acc.y + hv.y);
    float o2 = dv * (acc.z + hv.z);
    float o3 = dv * (acc.w + hv.w);
    if constexpr (BR) {
        float4 b = *reinterpret_cast<const float4*>(bias + sl * 4);
        o0 = fmaxf(o0 + b.x, 0.f);
        o1 = fmaxf(o1 + b.y, 0.f);
        o2 = fmaxf(o2 + b.z, 0.f);
        o3 = fmaxf(o3 + b.w, 0.f);
    }
    if constexpr (PS) {
        o0 *= dv; o1 *= dv; o2 *= dv; o3 *= dv;
    }
    *reinterpret_cast<float4*>(out + (size_t)v * 32 + sl * 4) = float4{o0, o1, o2, o3};
}

// ---------------------------------------------------------------------------
// agg32mm: agg32 (+b, relu, *dv) FUSED with @W (32x32) -> out = (D.x3)@W4.
// W staged in 4KB LDS; per node: 32 shfl broadcasts + 32 float4 FMAs,
// hidden under the latency-bound gather. Output row-major [N][32].
// ---------------------------------------------------------------------------
__global__ __launch_bounds__(256) void agg32mm_kernel(const float* __restrict__ h,
                                                      const int* __restrict__ off,
                                                      const int* __restrict__ csr,
                                                      const float* __restrict__ dinv,
                                                      const float* __restrict__ bias,
                                                      const float* __restrict__ W,
                                                      float* __restrict__ out, int n) {
    __shared__ float Ws[32 * 32];
    int tid = threadIdx.x;
    *reinterpret_cast<float4*>(&Ws[tid * 4]) =
        *reinterpret_cast<const float4*>(W + tid * 4);
    __syncthreads();

    int lane = tid & 63;
    int sl = lane & 7;
    int subbase = lane & ~7;
    int wave = tid >> 6;
    int v = blockIdx.x * 32 + wave * 8 + (lane >> 3);
    if (v >= n) return;

    float4 acc = agg32_gather(h, csr, off[v], off[v + 1], sl, subbase);

    float dv = dinv[v];
    float4 hv = *reinterpret_cast<const float4*>(h + (size_t)v * 32 + sl * 4);
    float4 b = *reinterpret_cast<const float4*>(bias + sl * 4);
    float o0 = fmaxf(dv * (acc.x + hv.x) + b.x, 0.f) * dv;
    float o1 = fmaxf(dv * (acc.y + hv.y) + b.y, 0.f) * dv;
    float o2 = fmaxf(dv * (acc.z + hv.z) + b.z, 0.f) * dv;
    float o3 = fmaxf(dv * (acc.w + hv.w) + b.w, 0.f) * dv;

    // y[4sl..4sl+3] = sum_k x[k] * W[k][4sl..]; x[k] broadcast via shfl.
    float y0 = 0.f, y1 = 0.f, y2 = 0.f, y3 = 0.f;
#pragma unroll
    for (int q = 0; q < 8; q++) {
        float x0 = __shfl(o0, subbase + q);
        float x1 = __shfl(o1, subbase + q);
        float x2 = __shfl(o2, subbase + q);
        float x3 = __shfl(o3, subbase + q);
        float4 w0 = *reinterpret_cast<const float4*>(&Ws[(4 * q + 0) * 32 + sl * 4]);
        float4 w1 = *reinterpret_cast<const float4*>(&Ws[(4 * q + 1) * 32 + sl * 4]);
        float4 w2 = *reinterpret_cast<const float4*>(&Ws[(4 * q + 2) * 32 + sl * 4]);
        float4 w3 = *reinterpret_cast<const float4*>(&Ws[(4 * q + 3) * 32 + sl * 4]);
        y0 += x0 * w0.x + x1 * w1.x + x2 * w2.x + x3 * w3.x;
        y1 += x0 * w0.y + x1 * w1.y + x2 * w2.y + x3 * w3.y;
        y2 += x0 * w0.z + x1 * w1.z + x2 * w2.z + x3 * w3.z;
        y3 += x0 * w0.w + x1 * w1.w + x2 * w2.w + x3 * w3.w;
    }
    *reinterpret_cast<float4*>(out + (size_t)v * 32 + sl * 4) = float4{y0, y1, y2, y3};
}

// ---------------------------------------------------------------------------
// agg32fin: raw agg32 FUSED with (t@W5+b5).relu @ Wl + bl -> out[v] scalar.
// W5 (8KB), b5, wl staged in LDS; lane owns 8 of 64 mid-cols; 8-lane
// shfl-xor reduce; lane0-of-8 writes.
// ---------------------------------------------------------------------------
__global__ __launch_bounds__(256) void agg32fin_kernel(const float* __restrict__ h,
                                                       const int* __restrict__ off,
                                                       const int* __restrict__ csr,
                                                       const float* __restrict__ dinv,
                                                       const float* __restrict__ W5,
                                                       const float* __restrict__ b5,
                                                       const float* __restrict__ Wl,
                                                       const float* __restrict__ bl,
                                                       float* __restrict__ out, int n) {
    __shared__ float W5s[32 * 64];
    __shared__ float b5s[64];
    __shared__ float wls[64];
    int tid = threadIdx.x;
    *reinterpret_cast<float4*>(&W5s[tid * 8]) =
        *reinterpret_cast<const float4*>(W5 + tid * 8);
    *reinterpret_cast<float4*>(&W5s[tid * 8 + 4]) =
        *reinterpret_cast<const float4*>(W5 + tid * 8 + 4);
    if (tid < 64) b5s[tid] = b5[tid];
    else if (tid < 128) wls[tid - 64] = Wl[tid - 64];
    __syncthreads();

    int lane = tid & 63;
    int sl = lane & 7;
    int subbase = lane & ~7;
    int wave = tid >> 6;
    int v = blockIdx.x * 32 + wave * 8 + (lane >> 3);
    if (v >= n) return;

    float4 acc = agg32_gather(h, csr, off[v], off[v + 1], sl, subbase);

    float dv = dinv[v];
    float4 hv = *reinterpret_cast<const float4*>(h + (size_t)v * 32 + sl * 4);
    float t0 = dv * (acc.x + hv.x);
    float t1 = dv * (acc.y + hv.y);
    float t2 = dv * (acc.z + hv.z);
    float t3 = dv * (acc.w + hv.w);

    // y[sl*8 .. sl*8+7] = sum_k t[k] * W5[k][sl*8..]
    float y0 = 0.f, y1 = 0.f, y2 = 0.f, y3 = 0.f;
    float y4 = 0.f, y5 = 0.f, y6 = 0.f, y7 = 0.f;
#pragma unroll
    for (int q = 0; q < 8; q++) {
        float x0 = __shfl(t0, subbase + q);
        float x1 = __shfl(t1, subbase + q);
        float x2 = __shfl(t2, subbase + q);
        float x3 = __shfl(t3, subbase + q);
#pragma unroll
        for (int r = 0; r < 4; r++) {
            float xv = (r == 0) ? x0 : (r == 1) ? x1 : (r == 2) ? x2 : x3;
            const float* wr = &W5s[(4 * q + r) * 64 + sl * 8];
            float4 wa = *reinterpret_cast<const float4*>(wr);
            float4 wb = *reinterpret_cast<const float4*>(wr + 4);
            y0 += xv * wa.x; y1 += xv * wa.y; y2 += xv * wa.z; y3 += xv * wa.w;
            y4 += xv * wb.x; y5 += xv * wb.y; y6 += xv * wb.z; y7 += xv * wb.w;
        }
    }
    float4 ba = *reinterpret_cast<const float4*>(&b5s[sl * 8]);
    float4 bb = *reinterpret_cast<const float4*>(&b5s[sl * 8 + 4]);
    float4 wa = *reinterpret_cast<const float4*>(&wls[sl * 8]);
    float4 wb = *reinterpret_cast<const float4*>(&wls[sl * 8 + 4]);
    float z = fmaxf(y0 + ba.x, 0.f) * wa.x + fmaxf(y1 + ba.y, 0.f) * wa.y +
              fmaxf(y2 + ba.z, 0.f) * wa.z + fmaxf(y3 + ba.w, 0.f) * wa.w +
              fmaxf(y4 + bb.x, 0.f) * wb.x + fmaxf(y5 + bb.y, 0.f) * wb.y +
              fmaxf(y6 + bb.z, 0.f) * wb.z + fmaxf(y7 + bb.w, 0.f) * wb.w;
    z += __shfl_xor(z, 4);
    z += __shfl_xor(z, 2);
    z += __shfl_xor(z, 1);
    if (sl == 0) out[v] = z + bl[0];
}

// ---------------------------------------------------------------------------
// Register-tiled GEMM: h[N,F] = x[N,K] @ W[K,F]; epilogue +bias/relu (BR),
// *dinv[row] (PS). KC=32 (KCP=36 breaks pow-2 banks).
// CIN/COUT: 0 = row-major, 32 = chunk-major [F/32][N][32] (for agg128x).
// ---------------------------------------------------------------------------
template <int K, int F, bool BR, bool PS, int CIN = 0, int COUT = 0>
__global__ __launch_bounds__(256, 4) void gemm_tiled(const float* __restrict__ x,
                                                     const float* __restrict__ W,
                                                     const float* __restrict__ bias,
                                                     const float* __restrict__ dinv,
                                                     float* __restrict__ h, int n) {
    constexpr int KC = 32;
    constexpr int KCP = 36;             // padded row stride (144 B, 16B-aligned)
    constexpr int ROWS = 64;
    constexpr int TPC = F / 4;
    constexpr int RT = 256 / TPC;
    constexpr int RPT = ROWS / RT;
    static_assert(K % KC == 0, "K must be a multiple of 32");

    __shared__ float Ws[KC * F];
    __shared__ float Xs[ROWS * KCP];

    const int tid = threadIdx.x;
    const int cb = (tid % TPC) * 4;
    const int tr = tid / TPC;
    const int row0 = blockIdx.x * ROWS;

    float acc[RPT][4];
#pragma unroll
    for (int r = 0; r < RPT; r++)
#pragma unroll
        for (int j = 0; j < 4; j++) acc[r][j] = 0.f;

#pragma unroll 1
    for (int k0 = 0; k0 < K; k0 += KC) {
        __syncthreads();
        {
            int r = tid >> 2;
            int kk = (tid & 3) * 8;
            int gr = row0 + r;
            float4 v0 = {0.f, 0.f, 0.f, 0.f}, v1 = {0.f, 0.f, 0.f, 0.f};
            if (gr < n) {
                if constexpr (CIN == 32) {
                    const float* xb = x + (size_t)(k0 >> 5) * n * 32 + (size_t)gr * 32 + kk;
                    v0 = *reinterpret_cast<const float4*>(xb);
                    v1 = *reinterpret_cast<const float4*>(xb + 4);
                } else {
                    v0 = *reinterpret_cast<const float4*>(x + (size_t)gr * K + k0 + kk);
                    v1 = *reinterpret_cast<const float4*>(x + (size_t)gr * K + k0 + kk + 4);
                }
            }
            *reinterpret_cast<float4*>(&Xs[r * KCP + kk]) = v0;
            *reinterpret_cast<float4*>(&Xs[r * KCP + kk + 4]) = v1;
        }
        for (int i = tid; i < KC * F / 4; i += 256) {
            *reinterpret_cast<float4*>(&Ws[i * 4]) =
                *reinterpret_cast<const float4*>(W + (size_t)k0 * F + i * 4);
        }
        __syncthreads();

#pragma unroll 4
        for (int kk4 = 0; kk4 < KC; kk4 += 4) {
            float4 xr[RPT];
#pragma unroll
            for (int r = 0; r < RPT; r++)
                xr[r] = *reinterpret_cast<const float4*>(&Xs[(tr * RPT + r) * KCP + kk4]);
#pragma unroll
            for (int j = 0; j < 4; j++) {
                float4 w = *reinterpret_cast<const float4*>(&Ws[(kk4 + j) * F + cb]);
#pragma unroll
                for (int r = 0; r < RPT; r++) {
                    float xv = (j == 0) ? xr[r].x : (j == 1) ? xr[r].y
                             : (j == 2) ? xr[r].z : xr[r].w;
                    acc[r][0] += xv * w.x;
                    acc[r][1] += xv * w.y;
                    acc[r][2] += xv * w.z;
                    acc[r][3] += xv * w.w;
                }
            }
        }
    }

    float4 b = float4{0.f, 0.f, 0.f, 0.f};
    if constexpr (BR) b = *reinterpret_cast<const float4*>(bias + cb);
#pragma unroll
    for (int r = 0; r < RPT; r++) {
        int row = row0 + tr * RPT + r;
        if (row < n) {
            float o0 = acc[r][0], o1 = acc[r][1], o2 = acc[r][2], o3 = acc[r][3];
            if constexpr (BR) {
                o0 = fmaxf(o0 + b.x, 0.f);
                o1 = fmaxf(o1 + b.y, 0.f);
                o2 = fmaxf(o2 + b.z, 0.f);
                o3 = fmaxf(o3 + b.w, 0.f);
            }
            if constexpr (PS) {
                float dv = dinv[row];
                o0 *= dv; o1 *= dv; o2 *= dv; o3 *= dv;
            }
            if constexpr (COUT == 32) {
                float* hb = h + (size_t)(cb >> 5) * n * 32 + (size_t)row * 32 + (cb & 31);
                *reinterpret_cast<float4*>(hb) = float4{o0, o1, o2, o3};
            } else {
                *reinterpret_cast<float4*>(&h[(size_t)row * F + cb]) = float4{o0, o1, o2, o3};
            }
        }
    }
}

extern "C" void kernel_launch(void* const* d_in, const int* in_sizes, int n_in,
                              void* d_out, int out_size, void* d_ws, size_t ws_size,
                              hipStream_t stream) {
    const float* x = (const float*)d_in[0];
    const int* ei = (const int*)d_in[1];
    const float* W1 = (const float*)d_in[3];
    const float* b1 = (const float*)d_in[4];
    const float* W2 = (const float*)d_in[5];
    const float* b2 = (const float*)d_in[6];
    const float* W3 = (const float*)d_in[7];
    const float* b3 = (const float*)d_in[8];
    const float* W4 = (const float*)d_in[9];
    const float* b4 = (const float*)d_in[10];
    const float* W5 = (const float*)d_in[11];
    const float* b5 = (const float*)d_in[12];
    const float* Wl = (const float*)d_in[13];
    const float* bl = (const float*)d_in[14];

    const int N = in_sizes[0] / 2;
    const int E = in_sizes[1] / 2;
    const int* src = ei;
    const int* dst = ei + E;

    char* wp = (char*)d_ws;
    auto alloc = [&](size_t bytes) -> void* {
        void* p = wp;
        wp += ((bytes + 255) / 256) * 256;
        return p;
    };
    int* cntq = (int*)alloc((size_t)N * 4 * 4);
    int* off = (int*)alloc((size_t)(N + 1) * 4);
    int* cursorq = (int*)alloc((size_t)N * 4 * 4);
    int* bsum = (int*)alloc(512 * 4);
    int* bpre = (int*)alloc(512 * 4);
    int* csr = (int*)alloc((size_t)E * 4);
    float* dinv = (float*)alloc((size_t)N * 4);
    float* xs2 = (float*)alloc((size_t)N * 2 * 4);
    float* bufA = (float*)alloc((size_t)N * 128 * 4);
    float* bufB = (float*)alloc((size_t)N * 128 * 4);

    const int gN = cdiv(N, 256);
    const int gE = cdiv(E, 256);
    const int nb = gN;
    const int gT = cdiv(N, 64);
    const int q1 = (N + 3) / 4;         // src quartile width

    // Ranged fill grid: 8 classes x 128 chunks.
    const int NCHUNK = 128;
    const int echunk = cdiv(E, NCHUNK);
    const int gR = 8 * NCHUNK;

    // agg128x grid: 8 classes (4 chunks x 2 dst-halves) x node-groups of 32.
    const int gX = 8 * cdiv((N + 1) / 2, 32);
    const int gA = cdiv(N, 32);

    // --- CSR build (src-quartile-bucketed: 4-way atomic spreading, R23) ---
    zero_i32<<<cdiv(4 * N, 256), 256, 0, stream>>>(cntq, 4 * N);
    count_q<<<gE, 256, 0, stream>>>(src, dst, cntq, E, q1);
    scan1q<<<nb, 256, 0, stream>>>(cntq, off, bsum, N);
    scan2<<<1, 512, 0, stream>>>(bsum, bpre, nb, off, N, E);
    scan3_fused<<<nb, 256, 0, stream>>>(cntq, bpre, off, cursorq, x, dinv, xs2, N);
    fill_ranged<<<gR, 256, 0, stream>>>(src, dst, cursorq, csr, E, N, echunk, q1);

    // --- Layer 1: fused agg [N,2] + gemm 2->128 (+b1, relu, *dinv) ---
    agg2mm_kernel<<<cdiv(N, 8), 256, 0, stream>>>(xs2, off, csr, dinv, W1, b1, bufA, N);
    // --- Layer 2: gemm 128->128 (raw, cm32 out), agg128x (+b2, relu, *dinv) ---
    gemm_tiled<128, 128, false, false, 0, 32><<<gT, 256, 0, stream>>>(bufA, W2, nullptr, nullptr, bufB, N);
    agg128x_kernel<true, true><<<gX, 256, 0, stream>>>(bufB, off, csr, dinv, b2, bufA, N);
    // --- Layer 3: gemm 128->32 (cm32 in), agg32mm (+b3, relu, *dinv, @W4) ---
    gemm_tiled<128, 32, false, false, 32, 0><<<gT, 256, 0, stream>>>(bufA, W3, nullptr, nullptr, bufB, N);
    agg32mm_kernel<<<gA, 256, 0, stream>>>(bufB, off, csr, dinv, b3, W4, bufA, N);
    // --- Layer 4: agg32 (+b4, relu, *dinv) -> D.x4 ---
    agg32_kernel<true, true><<<gA, 256, 0, stream>>>(bufA, off, csr, dinv, b4, bufB, N);
    // --- Layer 5: fused raw agg + (t@W5+b5).relu @ Wl + bl -> out ---
    agg32fin_kernel<<<gA, 256, 0, stream>>>(bufB, off, csr, dinv, W5, b5, Wl, bl, (float*)d_out, N);
}